// Round 5
// baseline (2127.392 us; speedup 1.0000x reference)
//
#include <hip/hip_runtime.h>
#include <hip/hip_bf16.h>
#include <float.h>

#define NSLOPE 0.2f

typedef __attribute__((ext_vector_type(8))) short short8v;
typedef __attribute__((ext_vector_type(4))) float f32x4;

__device__ inline void bsplit(float v, ushort& h, ushort& l) {
  __hip_bfloat16 hb = __float2bfloat16(v);
  float hf = __bfloat162float(hb);
  __hip_bfloat16 lb = __float2bfloat16(v - hf);
  h = *(ushort*)&hb; l = *(ushort*)&lb;
}

// ---------------- sum of squares per point ----------------
__global__ __launch_bounds__(256) void sumsq_kernel(const float* __restrict__ X, int ldx, int C,
                                                    float* __restrict__ xx, int total) {
  int t = blockIdx.x * 256 + threadIdx.x;
  if (t >= total) return;
  const float* p = X + (size_t)t * ldx;
  float s = 0.f;
  for (int c = 0; c < C; ++c) { float v = p[c]; s += v * v; }
  xx[t] = s;
}

// ---------------- combined-weight prep ----------------
__global__ __launch_bounds__(256) void wcprep_kernel(const float* __restrict__ W, int cin, int cout,
                                                     float* __restrict__ Wc) {
  int t = blockIdx.x * 256 + threadIdx.x;
  int tot = cin * 2 * cout;
  if (t >= tot) return;
  int c = t / (2 * cout), j = t % (2 * cout);
  float v;
  if (j < cout) v = W[c * cout + j];
  else          v = W[(cin + c) * cout + (j - cout)] - W[c * cout + (j - cout)];
  Wc[t] = v;
}

// ---------------- generic fp32 GEMM (small econv gemms) ----------------
__global__ __launch_bounds__(256) void gemm_kernel(const float* __restrict__ A, int lda,
                                                   const float* __restrict__ Bm, int ldb,
                                                   float* __restrict__ C, int ldc,
                                                   int M, int N, int K) {
  __shared__ float As[16][65];
  __shared__ float Bs[16][64];
  int tid = threadIdx.x;
  int tx = tid & 15, ty = tid >> 4;
  int row0 = blockIdx.y * 64, col0 = blockIdx.x * 64;
  float acc[4][4] = {};
  for (int k0 = 0; k0 < K; k0 += 16) {
    {
      int c = tid & 15, r4 = tid >> 4;
#pragma unroll
      for (int j = 0; j < 4; ++j) {
        int r = r4 + j * 16;
        float v = 0.f;
        if (k0 + c < K) v = A[(size_t)(row0 + r) * lda + k0 + c];
        As[c][r] = v;
      }
    }
    {
      int n = tid & 63, c4 = tid >> 6;
#pragma unroll
      for (int j = 0; j < 4; ++j) {
        int c = c4 + j * 4;
        float v = 0.f;
        if (k0 + c < K) v = Bm[(size_t)(k0 + c) * ldb + col0 + n];
        Bs[c][n] = v;
      }
    }
    __syncthreads();
#pragma unroll
    for (int kk = 0; kk < 16; ++kk) {
      float a[4], b[4];
#pragma unroll
      for (int i = 0; i < 4; ++i) a[i] = As[kk][ty * 4 + i];
#pragma unroll
      for (int j = 0; j < 4; ++j) b[j] = Bs[kk][tx * 4 + j];
#pragma unroll
      for (int i = 0; i < 4; ++i)
#pragma unroll
        for (int j = 0; j < 4; ++j) acc[i][j] += a[i] * b[j];
    }
    __syncthreads();
  }
#pragma unroll
  for (int i = 0; i < 4; ++i)
#pragma unroll
    for (int j = 0; j < 4; ++j)
      C[(size_t)(row0 + ty * 4 + i) * ldc + col0 + tx * 4 + j] = acc[i][j];
}

// ---------------- neg-dist GEMM ----------------
__global__ __launch_bounds__(256) void dist_kernel(const float* __restrict__ X, int ldx, int C,
                                                   const float* __restrict__ xx, float* __restrict__ D,
                                                   int b0, int N) {
  int batch = b0 + blockIdx.z;
  const float* Xb = X + (size_t)batch * N * ldx;
  const float* xxb = xx + (size_t)batch * N;
  float* Db = D + (size_t)blockIdx.z * N * N;
  __shared__ float Qs[16][65];
  __shared__ float Ps[16][65];
  int tid = threadIdx.x;
  int tx = tid & 15, ty = tid >> 4;
  int n0 = blockIdx.y * 64, m0 = blockIdx.x * 64;
  float acc[4][4] = {};
  for (int k0 = 0; k0 < C; k0 += 16) {
    int c = tid & 15, r4 = tid >> 4;
#pragma unroll
    for (int j = 0; j < 4; ++j) {
      int r = r4 + j * 16;
      float q = 0.f, p = 0.f;
      if (k0 + c < C) {
        q = Xb[(size_t)(n0 + r) * ldx + k0 + c];
        p = Xb[(size_t)(m0 + r) * ldx + k0 + c];
      }
      Qs[c][r] = q; Ps[c][r] = p;
    }
    __syncthreads();
#pragma unroll
    for (int kk = 0; kk < 16; ++kk) {
      float a[4], b[4];
#pragma unroll
      for (int i = 0; i < 4; ++i) a[i] = Qs[kk][ty * 4 + i];
#pragma unroll
      for (int j = 0; j < 4; ++j) b[j] = Ps[kk][tx * 4 + j];
#pragma unroll
      for (int i = 0; i < 4; ++i)
#pragma unroll
        for (int j = 0; j < 4; ++j) acc[i][j] += a[i] * b[j];
    }
    __syncthreads();
  }
#pragma unroll
  for (int i = 0; i < 4; ++i) {
    int n = n0 + ty * 4 + i;
    float xn = xxb[n];
#pragma unroll
    for (int j = 0; j < 4; ++j) {
      int m = m0 + tx * 4 + j;
      Db[(size_t)n * N + m] = 2.f * acc[i][j] - xn - xxb[m];
    }
  }
}

// ---------------- top-K: per-wave top-20 (no barriers) + single merge ----------------
__global__ __launch_bounds__(256) void topk_kernel(const float* __restrict__ D, int* __restrict__ idxo,
                                                   int b0, int N, int Ktop) {
  int n = blockIdx.x;
  int bz = blockIdx.y;
  const float* row = D + (size_t)bz * N * N + (size_t)n * N;
  int tid = threadIdx.x;
  int lane = tid & 63, w = tid >> 6;
  unsigned long long keys[8];
#pragma unroll
  for (int j = 0; j < 8; ++j) {
    int m = w * 512 + j * 64 + lane;
    float d = row[m];
    unsigned u = __float_as_uint(d);
    u = (u & 0x80000000u) ? ~u : (u | 0x80000000u);
    keys[j] = ((unsigned long long)u << 32) | (unsigned)(N - 1 - m);
  }
  __shared__ unsigned long long cand[80];
  unsigned long long mykey = 0ull;
  for (int k = 0; k < Ktop; ++k) {
    unsigned long long loc = keys[0];
#pragma unroll
    for (int j = 1; j < 8; ++j) loc = keys[j] > loc ? keys[j] : loc;
#pragma unroll
    for (int off = 32; off >= 1; off >>= 1) {
      unsigned long long o = __shfl_xor(loc, off, 64);
      loc = o > loc ? o : loc;
    }
    if (lane == k) mykey = loc;
#pragma unroll
    for (int j = 0; j < 8; ++j) if (keys[j] == loc) keys[j] = 0ull;
  }
  if (lane < Ktop) cand[w * Ktop + lane] = mykey;
  __syncthreads();
  if (w == 0) {
    unsigned long long c0 = cand[lane];
    unsigned long long c1 = (lane < 4 * Ktop - 64) ? cand[64 + lane] : 0ull;
    unsigned long long fin = 0ull;
    for (int k = 0; k < Ktop; ++k) {
      unsigned long long loc = c0 > c1 ? c0 : c1;
#pragma unroll
      for (int off = 32; off >= 1; off >>= 1) {
        unsigned long long o = __shfl_xor(loc, off, 64);
        loc = o > loc ? o : loc;
      }
      if (lane == k) fin = loc;
      if (c0 == loc) c0 = 0ull;
      if (c1 == loc) c1 = 0ull;
    }
    int* out = idxo + ((size_t)(b0 + bz) * N + n) * Ktop;
    if (lane < Ktop) out[lane] = N - 1 - (int)(unsigned)(fin & 0xFFFFFFFFu);
  }
}

// ---------------- gather + max over K + scale/bias/leaky (float4) ----------------
__global__ __launch_bounds__(256) void gathermax_kernel(const float* __restrict__ YZ, int ldyz, int cout,
                                                        const int* __restrict__ idxo,
                                                        const float* __restrict__ g, const float* __restrict__ bias,
                                                        float* __restrict__ outp, int ldo, int N, int Ktop,
                                                        int total4) {
  int t = blockIdx.x * 256 + threadIdx.x;
  if (t >= total4) return;
  int cq = cout >> 2;
  int dq = t % cq, bn = t / cq;
  int d0 = dq * 4;
  int b = bn / N;
  const int* ip = idxo + (size_t)bn * Ktop;
  float4 gv = *(const float4*)(g + d0);
  float4 bv = *(const float4*)(bias + d0);
  float4 zv = *(const float4*)(YZ + (size_t)bn * ldyz + cout + d0);
  bool px = gv.x >= 0.f, py = gv.y >= 0.f, pz = gv.z >= 0.f, pw = gv.w >= 0.f;
  float4 best;
  best.x = px ? -FLT_MAX : FLT_MAX;
  best.y = py ? -FLT_MAX : FLT_MAX;
  best.z = pz ? -FLT_MAX : FLT_MAX;
  best.w = pw ? -FLT_MAX : FLT_MAX;
  for (int k = 0; k < Ktop; ++k) {
    int m = ip[k];
    float4 y = *(const float4*)(YZ + ((size_t)b * N + m) * ldyz + d0);
    best.x = px ? fmaxf(best.x, y.x) : fminf(best.x, y.x);
    best.y = py ? fmaxf(best.y, y.y) : fminf(best.y, y.y);
    best.z = pz ? fmaxf(best.z, y.z) : fminf(best.z, y.z);
    best.w = pw ? fmaxf(best.w, y.w) : fminf(best.w, y.w);
  }
  float4 o;
  float h;
  h = (best.x + zv.x) * gv.x + bv.x; o.x = h >= 0.f ? h : NSLOPE * h;
  h = (best.y + zv.y) * gv.y + bv.y; o.y = h >= 0.f ? h : NSLOPE * h;
  h = (best.z + zv.z) * gv.z + bv.z; o.z = h >= 0.f ? h : NSLOPE * h;
  h = (best.w + zv.w) * gv.w + bv.w; o.w = h >= 0.f ? h : NSLOPE * h;
  *(float4*)(outp + (size_t)bn * ldo + d0) = o;
}

// ---------------- final GEMM via split-bf16 MFMA, fused fp32->hi/lo staging ----------------
// D[d][m] = sum_k W[k][d] * XC[m][k]; A-operand = W (row=d), B-operand = XC (col=m).
// M=16384, Nd=1024, K=512. Tile 128(d) x 128(m), BK=32, 4 waves (2x2).
__global__ __launch_bounds__(256) void mfma_out_kernel(const float* __restrict__ XC,
                                                       const float* __restrict__ W,
                                                       const float* __restrict__ g,
                                                       const float* __restrict__ bias,
                                                       float* __restrict__ outp) {
  __shared__ ushort Ws_hi[128 * 40];
  __shared__ ushort Ws_lo[128 * 40];
  __shared__ ushort Xs_hi[128 * 40];
  __shared__ ushort Xs_lo[128 * 40];
  const int tid = threadIdx.x;
  const int lane = tid & 63, w = tid >> 6;
  const int wd = w & 1, wn = w >> 1;
  const int col0 = blockIdx.x * 128;  // d
  const int row0 = blockIdx.y * 128;  // m
  f32x4 acc[4][4] = {};

  for (int k0 = 0; k0 < 512; k0 += 32) {
    // stage XC tile [128 m][32 k] with on-the-fly hi/lo split (float4 loads)
#pragma unroll
    for (int e = 0; e < 4; ++e) {
      int flat = tid + e * 256;          // 0..1023 float4 units
      int r = flat >> 3;                 // 0..127
      int c4 = (flat & 7) * 4;           // 0,4,...,28
      float4 v = *(const float4*)(XC + (size_t)(row0 + r) * 512 + k0 + c4);
      ushort4 h, l;
      bsplit(v.x, h.x, l.x); bsplit(v.y, h.y, l.y);
      bsplit(v.z, h.z, l.z); bsplit(v.w, h.w, l.w);
      *(ushort4*)&Xs_hi[r * 40 + c4] = h;
      *(ushort4*)&Xs_lo[r * 40 + c4] = l;
    }
    // stage W tile transposed [128 d][32 k] with on-the-fly hi/lo split
#pragma unroll
    for (int e = 0; e < 4; ++e) {
      int flat = tid + e * 256;          // 0..1023 units (16k-pairs x 64 d-pairs)
      int k = (flat >> 6) * 2;
      int c2 = (flat & 63) * 2;
      float2 v0 = *(const float2*)(W + (size_t)(k0 + k) * 1024 + col0 + c2);
      float2 v1 = *(const float2*)(W + (size_t)(k0 + k + 1) * 1024 + col0 + c2);
      ushort h00, h01, h10, h11, l00, l01, l10, l11;
      bsplit(v0.x, h00, l00); bsplit(v0.y, h01, l01);
      bsplit(v1.x, h10, l10); bsplit(v1.y, h11, l11);
      *(uint*)&Ws_hi[c2 * 40 + k]       = (uint)h00 | ((uint)h10 << 16);
      *(uint*)&Ws_hi[(c2 + 1) * 40 + k] = (uint)h01 | ((uint)h11 << 16);
      *(uint*)&Ws_lo[c2 * 40 + k]       = (uint)l00 | ((uint)l10 << 16);
      *(uint*)&Ws_lo[(c2 + 1) * 40 + k] = (uint)l01 | ((uint)l11 << 16);
    }
    __syncthreads();
    short8v wh[4], wl[4], xh[4], xl[4];
    int kg = (lane >> 4) * 8;
    int lr = lane & 15;
#pragma unroll
    for (int i = 0; i < 4; ++i) {
      wh[i] = *(const short8v*)&Ws_hi[(wd * 64 + i * 16 + lr) * 40 + kg];
      wl[i] = *(const short8v*)&Ws_lo[(wd * 64 + i * 16 + lr) * 40 + kg];
      xh[i] = *(const short8v*)&Xs_hi[(wn * 64 + i * 16 + lr) * 40 + kg];
      xl[i] = *(const short8v*)&Xs_lo[(wn * 64 + i * 16 + lr) * 40 + kg];
    }
#pragma unroll
    for (int i = 0; i < 4; ++i)
#pragma unroll
      for (int j = 0; j < 4; ++j) {
        acc[i][j] = __builtin_amdgcn_mfma_f32_16x16x32_bf16(wh[i], xh[j], acc[i][j], 0, 0, 0);
        acc[i][j] = __builtin_amdgcn_mfma_f32_16x16x32_bf16(wh[i], xl[j], acc[i][j], 0, 0, 0);
        acc[i][j] = __builtin_amdgcn_mfma_f32_16x16x32_bf16(wl[i], xh[j], acc[i][j], 0, 0, 0);
      }
    __syncthreads();
  }
  int fq = lane >> 4, fr = lane & 15;
#pragma unroll
  for (int i = 0; i < 4; ++i) {
#pragma unroll
    for (int r = 0; r < 4; ++r) {
      int d = col0 + wd * 64 + i * 16 + fq * 4 + r;
      float gv = g[d], bv = bias[d];
#pragma unroll
      for (int j = 0; j < 4; ++j) {
        int mrow = row0 + wn * 64 + j * 16 + fr;
        int batch = mrow >> 11, n = mrow & 2047;
        float h = acc[i][j][r] * gv + bv;
        h = h >= 0.f ? h : NSLOPE * h;
        outp[(((size_t)batch << 10) + d) * 2048 + n] = h;
      }
    }
  }
}

extern "C" void kernel_launch(void* const* d_in, const int* in_sizes, int n_in,
                              void* d_out, int out_size, void* d_ws, size_t ws_size,
                              hipStream_t stream) {
  const int B = 8, N = 2048, Ktop = 20;
  const int M = B * N;  // 16384

  const float* pts = (const float*)d_in[0];
  const float* W1 = (const float*)d_in[1];  const float* g1 = (const float*)d_in[2];  const float* b1 = (const float*)d_in[3];
  const float* W2 = (const float*)d_in[4];  const float* g2 = (const float*)d_in[5];  const float* b2 = (const float*)d_in[6];
  const float* W3 = (const float*)d_in[7];  const float* g3 = (const float*)d_in[8];  const float* b3 = (const float*)d_in[9];
  const float* W4 = (const float*)d_in[10]; const float* g4 = (const float*)d_in[11]; const float* b4 = (const float*)d_in[12];
  const float* W5 = (const float*)d_in[13]; const float* g5 = (const float*)d_in[14]; const float* b5 = (const float*)d_in[15];

  float* p = (float*)d_ws;
  float* XC = p;  p += (size_t)M * 512;        // concat feature buffer [x1|x2|x3|x4]
  float* Wc = p;  p += 128 * 512;              // combined weight, max cin*2cout
  float* xx = p;  p += M;                      // per-point sum of squares
  int* idxb = (int*)p; p = (float*)(idxb + (size_t)M * Ktop);
  float* shared = p;                           // D / YZ overlap (disjoint lifetimes)
  size_t shared_bytes = ws_size - (size_t)((char*)shared - (char*)d_ws);
  float* D = shared;
  float* YZ = shared;
  int chunk = (int)(shared_bytes / ((size_t)N * N * sizeof(float)));
  if (chunk > B) chunk = B;
  if (chunk < 1) chunk = 1;

  auto knn = [&](const float* Xp, int ldx, int C) {
    sumsq_kernel<<<(M + 255) / 256, 256, 0, stream>>>(Xp, ldx, C, xx, M);
    for (int b0 = 0; b0 < B; b0 += chunk) {
      int nb = (B - b0 < chunk) ? (B - b0) : chunk;
      dist_kernel<<<dim3(N / 64, N / 64, nb), 256, 0, stream>>>(Xp, ldx, C, xx, D, b0, N);
      topk_kernel<<<dim3(N, nb), 256, 0, stream>>>(D, idxb, b0, N, Ktop);
    }
  };

  auto econv = [&](const float* Xp, int ldx, int cin, int cout,
                   const float* W, const float* g, const float* bb, float* outp) {
    int tot = cin * 2 * cout;
    wcprep_kernel<<<(tot + 255) / 256, 256, 0, stream>>>(W, cin, cout, Wc);
    gemm_kernel<<<dim3(2 * cout / 64, M / 64), 256, 0, stream>>>(Xp, ldx, Wc, 2 * cout, YZ, 2 * cout, M, 2 * cout, cin);
    int total4 = B * N * (cout / 4);
    gathermax_kernel<<<(total4 + 255) / 256, 256, 0, stream>>>(YZ, 2 * cout, cout, idxb, g, bb, outp, 512, N, Ktop, total4);
  };

  knn(pts, 3, 3);
  econv(pts, 3, 3, 64, W1, g1, b1, XC + 0);
  knn(XC + 0, 512, 64);
  econv(XC + 0, 512, 64, 64, W2, g2, b2, XC + 64);
  knn(XC + 64, 512, 64);
  econv(XC + 64, 512, 64, 128, W3, g3, b3, XC + 128);
  knn(XC + 128, 512, 128);
  econv(XC + 128, 512, 128, 256, W4, g4, b4, XC + 256);

  // final: fused split-bf16 MFMA GEMM (no extra ws buffers)
  mfma_out_kernel<<<dim3(1024 / 128, M / 128), 256, 0, stream>>>(XC, W5, g5, b5, (float*)d_out);
}

// Round 7
// 1160.571 us; speedup vs baseline: 1.8331x; 1.8331x over previous
//
#include <hip/hip_runtime.h>
#include <hip/hip_bf16.h>
#include <float.h>

#define NSLOPE 0.2f

typedef __attribute__((ext_vector_type(8))) short short8v;
typedef __attribute__((ext_vector_type(4))) float f32x4;

__device__ inline void bsplit(float v, ushort& h, ushort& l) {
  __hip_bfloat16 hb = __float2bfloat16(v);
  float hf = __bfloat162float(hb);
  __hip_bfloat16 lb = __float2bfloat16(v - hf);
  h = *(ushort*)&hb; l = *(ushort*)&lb;
}

// ---------------- sum of squares per point ----------------
__global__ __launch_bounds__(256) void sumsq_kernel(const float* __restrict__ X, int ldx, int C,
                                                    float* __restrict__ xx, int total) {
  int t = blockIdx.x * 256 + threadIdx.x;
  if (t >= total) return;
  const float* p = X + (size_t)t * ldx;
  float s = 0.f;
  for (int c = 0; c < C; ++c) { float v = p[c]; s += v * v; }
  xx[t] = s;
}

// ---------------- combined-weight prep ----------------
__global__ __launch_bounds__(256) void wcprep_kernel(const float* __restrict__ W, int cin, int cout,
                                                     float* __restrict__ Wc) {
  int t = blockIdx.x * 256 + threadIdx.x;
  int tot = cin * 2 * cout;
  if (t >= tot) return;
  int c = t / (2 * cout), j = t % (2 * cout);
  float v;
  if (j < cout) v = W[c * cout + j];
  else          v = W[(cin + c) * cout + (j - cout)] - W[c * cout + (j - cout)];
  Wc[t] = v;
}

// ---------------- generic fp32 GEMM (small econv gemms) ----------------
__global__ __launch_bounds__(256) void gemm_kernel(const float* __restrict__ A, int lda,
                                                   const float* __restrict__ Bm, int ldb,
                                                   float* __restrict__ C, int ldc,
                                                   int M, int N, int K) {
  __shared__ float As[16][65];
  __shared__ float Bs[16][64];
  int tid = threadIdx.x;
  int tx = tid & 15, ty = tid >> 4;
  int row0 = blockIdx.y * 64, col0 = blockIdx.x * 64;
  float acc[4][4] = {};
  for (int k0 = 0; k0 < K; k0 += 16) {
    {
      int c = tid & 15, r4 = tid >> 4;
#pragma unroll
      for (int j = 0; j < 4; ++j) {
        int r = r4 + j * 16;
        float v = 0.f;
        if (k0 + c < K) v = A[(size_t)(row0 + r) * lda + k0 + c];
        As[c][r] = v;
      }
    }
    {
      int n = tid & 63, c4 = tid >> 6;
#pragma unroll
      for (int j = 0; j < 4; ++j) {
        int c = c4 + j * 4;
        float v = 0.f;
        if (k0 + c < K) v = Bm[(size_t)(k0 + c) * ldb + col0 + n];
        Bs[c][n] = v;
      }
    }
    __syncthreads();
#pragma unroll
    for (int kk = 0; kk < 16; ++kk) {
      float a[4], b[4];
#pragma unroll
      for (int i = 0; i < 4; ++i) a[i] = As[kk][ty * 4 + i];
#pragma unroll
      for (int j = 0; j < 4; ++j) b[j] = Bs[kk][tx * 4 + j];
#pragma unroll
      for (int i = 0; i < 4; ++i)
#pragma unroll
        for (int j = 0; j < 4; ++j) acc[i][j] += a[i] * b[j];
    }
    __syncthreads();
  }
#pragma unroll
  for (int i = 0; i < 4; ++i)
#pragma unroll
    for (int j = 0; j < 4; ++j)
      C[(size_t)(row0 + ty * 4 + i) * ldc + col0 + tx * 4 + j] = acc[i][j];
}

// ---------------- neg-dist GEMM ----------------
__global__ __launch_bounds__(256) void dist_kernel(const float* __restrict__ X, int ldx, int C,
                                                   const float* __restrict__ xx, float* __restrict__ D,
                                                   int b0, int N) {
  int batch = b0 + blockIdx.z;
  const float* Xb = X + (size_t)batch * N * ldx;
  const float* xxb = xx + (size_t)batch * N;
  float* Db = D + (size_t)blockIdx.z * N * N;
  __shared__ float Qs[16][65];
  __shared__ float Ps[16][65];
  int tid = threadIdx.x;
  int tx = tid & 15, ty = tid >> 4;
  int n0 = blockIdx.y * 64, m0 = blockIdx.x * 64;
  float acc[4][4] = {};
  for (int k0 = 0; k0 < C; k0 += 16) {
    int c = tid & 15, r4 = tid >> 4;
#pragma unroll
    for (int j = 0; j < 4; ++j) {
      int r = r4 + j * 16;
      float q = 0.f, p = 0.f;
      if (k0 + c < C) {
        q = Xb[(size_t)(n0 + r) * ldx + k0 + c];
        p = Xb[(size_t)(m0 + r) * ldx + k0 + c];
      }
      Qs[c][r] = q; Ps[c][r] = p;
    }
    __syncthreads();
#pragma unroll
    for (int kk = 0; kk < 16; ++kk) {
      float a[4], b[4];
#pragma unroll
      for (int i = 0; i < 4; ++i) a[i] = Qs[kk][ty * 4 + i];
#pragma unroll
      for (int j = 0; j < 4; ++j) b[j] = Ps[kk][tx * 4 + j];
#pragma unroll
      for (int i = 0; i < 4; ++i)
#pragma unroll
        for (int j = 0; j < 4; ++j) acc[i][j] += a[i] * b[j];
    }
    __syncthreads();
  }
#pragma unroll
  for (int i = 0; i < 4; ++i) {
    int n = n0 + ty * 4 + i;
    float xn = xxb[n];
#pragma unroll
    for (int j = 0; j < 4; ++j) {
      int m = m0 + tx * 4 + j;
      Db[(size_t)n * N + m] = 2.f * acc[i][j] - xn - xxb[m];
    }
  }
}

// ---------------- top-K via MSB radix select (set semantics; exact lax.top_k tie-break) ----------------
// One block per (row, batch). 256 threads x 8 elements. Output index order is arbitrary
// (consumer gathermax is permutation-invariant); the SET matches lax.top_k exactly.
__global__ __launch_bounds__(256) void topk_kernel(const float* __restrict__ D, int* __restrict__ idxo,
                                                   int b0, int N, int Ktop) {
  int n = blockIdx.x;
  int bz = blockIdx.y;
  const float* row = D + (size_t)bz * N * N + (size_t)n * N;
  int tid = threadIdx.x;

  // load 8 elements as order-preserving sortable u32
  unsigned u[8];
#pragma unroll
  for (int j = 0; j < 8; ++j) {
    float d = row[j * 256 + tid];
    unsigned x = __float_as_uint(d);
    u[j] = (x & 0x80000000u) ? ~x : (x | 0x80000000u);
  }

  __shared__ unsigned h4[4][256];   // per-wave sub-histograms
  __shared__ unsigned binc[256];
  __shared__ unsigned sufs[256];
  __shared__ unsigned sel[3];       // bin, krem, cnt
  __shared__ int cnt_g, eqn;
  __shared__ int eqlist[2048];

  unsigned prefix = 0, Tmask = 0;
  int krem = Ktop;
  bool done = false;
  unsigned* myh = h4[tid >> 6];

  for (int lev = 0; lev < 4 && !done; ++lev) {
    int shift = 24 - lev * 8;
    h4[0][tid] = 0; h4[1][tid] = 0; h4[2][tid] = 0; h4[3][tid] = 0;
    __syncthreads();
    unsigned pmask = Tmask;  // bits resolved before this level
#pragma unroll
    for (int j = 0; j < 8; ++j)
      if ((u[j] & pmask) == prefix) atomicAdd(&myh[(u[j] >> shift) & 255], 1u);
    __syncthreads();
    unsigned c = h4[0][tid] + h4[1][tid] + h4[2][tid] + h4[3][tid];
    binc[tid] = c; sufs[tid] = c;
    __syncthreads();
    for (int st = 1; st < 256; st <<= 1) {
      unsigned add = (tid + st < 256) ? sufs[tid + st] : 0u;
      __syncthreads();
      sufs[tid] += add;
      __syncthreads();
    }
    unsigned above = sufs[tid] - binc[tid];  // count of digits > tid (among matching)
    if (above < (unsigned)krem && (unsigned)krem <= sufs[tid]) {
      sel[0] = (unsigned)tid; sel[1] = (unsigned)krem - above; sel[2] = binc[tid];
    }
    __syncthreads();
    prefix |= sel[0] << shift;
    krem = (int)sel[1];
    Tmask = 0xFFFFFFFFu << shift;
    done = (sel[2] == (unsigned)krem);   // all remaining matches are included -> stop
    __syncthreads();
  }

  if (tid == 0) { cnt_g = 0; eqn = 0; }
  __syncthreads();
  int* out = idxo + ((size_t)(b0 + bz) * N + n) * Ktop;
#pragma unroll
  for (int j = 0; j < 8; ++j) {
    int m = j * 256 + tid;
    unsigned um = u[j] & Tmask;
    if (um > prefix) {
      out[atomicAdd(&cnt_g, 1)] = m;
    } else if (um == prefix) {
      eqlist[atomicAdd(&eqn, 1)] = m;
    }
  }
  __syncthreads();
  int cg = cnt_g, ne = eqn, ke = krem;   // cg == Ktop - ke
  if (ne == ke) {
    if (tid < ne) out[cg + tid] = eqlist[tid];
  } else if (tid == 0) {
    // value ties at the boundary: take ke smallest indices (lax.top_k tie-break)
    int last = -1;
    for (int s = 0; s < ke; ++s) {
      int mn = 0x7FFFFFFF;
      for (int i2 = 0; i2 < ne; ++i2) {
        int v = eqlist[i2];
        if (v > last && v < mn) mn = v;
      }
      out[cg + s] = mn; last = mn;
    }
  }
}

// ---------------- gather + max over K + scale/bias/leaky (float4) ----------------
__global__ __launch_bounds__(256) void gathermax_kernel(const float* __restrict__ YZ, int ldyz, int cout,
                                                        const int* __restrict__ idxo,
                                                        const float* __restrict__ g, const float* __restrict__ bias,
                                                        float* __restrict__ outp, int ldo, int N, int Ktop,
                                                        int total4) {
  int t = blockIdx.x * 256 + threadIdx.x;
  if (t >= total4) return;
  int cq = cout >> 2;
  int dq = t % cq, bn = t / cq;
  int d0 = dq * 4;
  int b = bn / N;
  const int* ip = idxo + (size_t)bn * Ktop;
  float4 gv = *(const float4*)(g + d0);
  float4 bv = *(const float4*)(bias + d0);
  float4 zv = *(const float4*)(YZ + (size_t)bn * ldyz + cout + d0);
  bool px = gv.x >= 0.f, py = gv.y >= 0.f, pz = gv.z >= 0.f, pw = gv.w >= 0.f;
  float4 best;
  best.x = px ? -FLT_MAX : FLT_MAX;
  best.y = py ? -FLT_MAX : FLT_MAX;
  best.z = pz ? -FLT_MAX : FLT_MAX;
  best.w = pw ? -FLT_MAX : FLT_MAX;
  for (int k = 0; k < Ktop; ++k) {
    int m = ip[k];
    float4 y = *(const float4*)(YZ + ((size_t)b * N + m) * ldyz + d0);
    best.x = px ? fmaxf(best.x, y.x) : fminf(best.x, y.x);
    best.y = py ? fmaxf(best.y, y.y) : fminf(best.y, y.y);
    best.z = pz ? fmaxf(best.z, y.z) : fminf(best.z, y.z);
    best.w = pw ? fmaxf(best.w, y.w) : fminf(best.w, y.w);
  }
  float4 o;
  float h;
  h = (best.x + zv.x) * gv.x + bv.x; o.x = h >= 0.f ? h : NSLOPE * h;
  h = (best.y + zv.y) * gv.y + bv.y; o.y = h >= 0.f ? h : NSLOPE * h;
  h = (best.z + zv.z) * gv.z + bv.z; o.z = h >= 0.f ? h : NSLOPE * h;
  h = (best.w + zv.w) * gv.w + bv.w; o.w = h >= 0.f ? h : NSLOPE * h;
  *(float4*)(outp + (size_t)bn * ldo + d0) = o;
}

// ---------------- final GEMM via split-bf16 MFMA, fused fp32->hi/lo staging ----------------
__global__ __launch_bounds__(256) void mfma_out_kernel(const float* __restrict__ XC,
                                                       const float* __restrict__ W,
                                                       const float* __restrict__ g,
                                                       const float* __restrict__ bias,
                                                       float* __restrict__ outp) {
  __shared__ ushort Ws_hi[128 * 40];
  __shared__ ushort Ws_lo[128 * 40];
  __shared__ ushort Xs_hi[128 * 40];
  __shared__ ushort Xs_lo[128 * 40];
  const int tid = threadIdx.x;
  const int lane = tid & 63, w = tid >> 6;
  const int wd = w & 1, wn = w >> 1;
  const int col0 = blockIdx.x * 128;  // d
  const int row0 = blockIdx.y * 128;  // m
  f32x4 acc[4][4] = {};

  for (int k0 = 0; k0 < 512; k0 += 32) {
#pragma unroll
    for (int e = 0; e < 4; ++e) {
      int flat = tid + e * 256;
      int r = flat >> 3;
      int c4 = (flat & 7) * 4;
      float4 v = *(const float4*)(XC + (size_t)(row0 + r) * 512 + k0 + c4);
      ushort4 h, l;
      bsplit(v.x, h.x, l.x); bsplit(v.y, h.y, l.y);
      bsplit(v.z, h.z, l.z); bsplit(v.w, h.w, l.w);
      *(ushort4*)&Xs_hi[r * 40 + c4] = h;
      *(ushort4*)&Xs_lo[r * 40 + c4] = l;
    }
#pragma unroll
    for (int e = 0; e < 4; ++e) {
      int flat = tid + e * 256;
      int k = (flat >> 6) * 2;
      int c2 = (flat & 63) * 2;
      float2 v0 = *(const float2*)(W + (size_t)(k0 + k) * 1024 + col0 + c2);
      float2 v1 = *(const float2*)(W + (size_t)(k0 + k + 1) * 1024 + col0 + c2);
      ushort h00, h01, h10, h11, l00, l01, l10, l11;
      bsplit(v0.x, h00, l00); bsplit(v0.y, h01, l01);
      bsplit(v1.x, h10, l10); bsplit(v1.y, h11, l11);
      *(uint*)&Ws_hi[c2 * 40 + k]       = (uint)h00 | ((uint)h10 << 16);
      *(uint*)&Ws_hi[(c2 + 1) * 40 + k] = (uint)h01 | ((uint)h11 << 16);
      *(uint*)&Ws_lo[c2 * 40 + k]       = (uint)l00 | ((uint)l10 << 16);
      *(uint*)&Ws_lo[(c2 + 1) * 40 + k] = (uint)l01 | ((uint)l11 << 16);
    }
    __syncthreads();
    short8v wh[4], wl[4], xh[4], xl[4];
    int kg = (lane >> 4) * 8;
    int lr = lane & 15;
#pragma unroll
    for (int i = 0; i < 4; ++i) {
      wh[i] = *(const short8v*)&Ws_hi[(wd * 64 + i * 16 + lr) * 40 + kg];
      wl[i] = *(const short8v*)&Ws_lo[(wd * 64 + i * 16 + lr) * 40 + kg];
      xh[i] = *(const short8v*)&Xs_hi[(wn * 64 + i * 16 + lr) * 40 + kg];
      xl[i] = *(const short8v*)&Xs_lo[(wn * 64 + i * 16 + lr) * 40 + kg];
    }
#pragma unroll
    for (int i = 0; i < 4; ++i)
#pragma unroll
      for (int j = 0; j < 4; ++j) {
        acc[i][j] = __builtin_amdgcn_mfma_f32_16x16x32_bf16(wh[i], xh[j], acc[i][j], 0, 0, 0);
        acc[i][j] = __builtin_amdgcn_mfma_f32_16x16x32_bf16(wh[i], xl[j], acc[i][j], 0, 0, 0);
        acc[i][j] = __builtin_amdgcn_mfma_f32_16x16x32_bf16(wl[i], xh[j], acc[i][j], 0, 0, 0);
      }
    __syncthreads();
  }
  int fq = lane >> 4, fr = lane & 15;
#pragma unroll
  for (int i = 0; i < 4; ++i) {
#pragma unroll
    for (int r = 0; r < 4; ++r) {
      int d = col0 + wd * 64 + i * 16 + fq * 4 + r;
      float gv = g[d], bv = bias[d];
#pragma unroll
      for (int j = 0; j < 4; ++j) {
        int mrow = row0 + wn * 64 + j * 16 + fr;
        int batch = mrow >> 11, n = mrow & 2047;
        float h = acc[i][j][r] * gv + bv;
        h = h >= 0.f ? h : NSLOPE * h;
        outp[(((size_t)batch << 10) + d) * 2048 + n] = h;
      }
    }
  }
}

extern "C" void kernel_launch(void* const* d_in, const int* in_sizes, int n_in,
                              void* d_out, int out_size, void* d_ws, size_t ws_size,
                              hipStream_t stream) {
  const int B = 8, N = 2048, Ktop = 20;
  const int M = B * N;  // 16384

  const float* pts = (const float*)d_in[0];
  const float* W1 = (const float*)d_in[1];  const float* g1 = (const float*)d_in[2];  const float* b1 = (const float*)d_in[3];
  const float* W2 = (const float*)d_in[4];  const float* g2 = (const float*)d_in[5];  const float* b2 = (const float*)d_in[6];
  const float* W3 = (const float*)d_in[7];  const float* g3 = (const float*)d_in[8];  const float* b3 = (const float*)d_in[9];
  const float* W4 = (const float*)d_in[10]; const float* g4 = (const float*)d_in[11]; const float* b4 = (const float*)d_in[12];
  const float* W5 = (const float*)d_in[13]; const float* g5 = (const float*)d_in[14]; const float* b5 = (const float*)d_in[15];

  float* p = (float*)d_ws;
  float* XC = p;  p += (size_t)M * 512;        // concat feature buffer [x1|x2|x3|x4]
  float* Wc = p;  p += 128 * 512;              // combined weight, max cin*2cout
  float* xx = p;  p += M;                      // per-point sum of squares
  int* idxb = (int*)p; p = (float*)(idxb + (size_t)M * Ktop);
  float* shared = p;                           // D / YZ overlap (disjoint lifetimes)
  size_t shared_bytes = ws_size - (size_t)((char*)shared - (char*)d_ws);
  float* D = shared;
  float* YZ = shared;
  int chunk = (int)(shared_bytes / ((size_t)N * N * sizeof(float)));
  if (chunk > B) chunk = B;
  if (chunk < 1) chunk = 1;

  auto knn = [&](const float* Xp, int ldx, int C) {
    sumsq_kernel<<<(M + 255) / 256, 256, 0, stream>>>(Xp, ldx, C, xx, M);
    for (int b0 = 0; b0 < B; b0 += chunk) {
      int nb = (B - b0 < chunk) ? (B - b0) : chunk;
      dist_kernel<<<dim3(N / 64, N / 64, nb), 256, 0, stream>>>(Xp, ldx, C, xx, D, b0, N);
      topk_kernel<<<dim3(N, nb), 256, 0, stream>>>(D, idxb, b0, N, Ktop);
    }
  };

  auto econv = [&](const float* Xp, int ldx, int cin, int cout,
                   const float* W, const float* g, const float* bb, float* outp) {
    int tot = cin * 2 * cout;
    wcprep_kernel<<<(tot + 255) / 256, 256, 0, stream>>>(W, cin, cout, Wc);
    gemm_kernel<<<dim3(2 * cout / 64, M / 64), 256, 0, stream>>>(Xp, ldx, Wc, 2 * cout, YZ, 2 * cout, M, 2 * cout, cin);
    int total4 = B * N * (cout / 4);
    gathermax_kernel<<<(total4 + 255) / 256, 256, 0, stream>>>(YZ, 2 * cout, cout, idxb, g, bb, outp, 512, N, Ktop, total4);
  };

  knn(pts, 3, 3);
  econv(pts, 3, 3, 64, W1, g1, b1, XC + 0);
  knn(XC + 0, 512, 64);
  econv(XC + 0, 512, 64, 64, W2, g2, b2, XC + 64);
  knn(XC + 64, 512, 64);
  econv(XC + 64, 512, 64, 128, W3, g3, b3, XC + 128);
  knn(XC + 128, 512, 128);
  econv(XC + 128, 512, 128, 256, W4, g4, b4, XC + 256);

  // final: fused split-bf16 MFMA GEMM (no extra ws buffers)
  mfma_out_kernel<<<dim3(1024 / 128, M / 128), 256, 0, stream>>>(XC, W5, g5, b5, (float*)d_out);
}

// Round 9
// 971.914 us; speedup vs baseline: 2.1889x; 1.1941x over previous
//
#include <hip/hip_runtime.h>
#include <hip/hip_bf16.h>
#include <float.h>

#define NSLOPE 0.2f

typedef __attribute__((ext_vector_type(8))) short short8v;
typedef __attribute__((ext_vector_type(4))) float f32x4;

__device__ inline void bsplit(float v, ushort& h, ushort& l) {
  __hip_bfloat16 hb = __float2bfloat16(v);
  float hf = __bfloat162float(hb);
  __hip_bfloat16 lb = __float2bfloat16(v - hf);
  h = *(ushort*)&hb; l = *(ushort*)&lb;
}

// ---------------- sum of squares per point ----------------
__global__ __launch_bounds__(256) void sumsq_kernel(const float* __restrict__ X, int ldx, int C,
                                                    float* __restrict__ xx, int total) {
  int t = blockIdx.x * 256 + threadIdx.x;
  if (t >= total) return;
  const float* p = X + (size_t)t * ldx;
  float s = 0.f;
  for (int c = 0; c < C; ++c) { float v = p[c]; s += v * v; }
  xx[t] = s;
}

// ---------------- combined-weight prep ----------------
__global__ __launch_bounds__(256) void wcprep_kernel(const float* __restrict__ W, int cin, int cout,
                                                     float* __restrict__ Wc) {
  int t = blockIdx.x * 256 + threadIdx.x;
  int tot = cin * 2 * cout;
  if (t >= tot) return;
  int c = t / (2 * cout), j = t % (2 * cout);
  float v;
  if (j < cout) v = W[c * cout + j];
  else          v = W[(cin + c) * cout + (j - cout)] - W[c * cout + (j - cout)];
  Wc[t] = v;
}

// ---------------- generic fp32 GEMM (small econv gemms) ----------------
__global__ __launch_bounds__(256) void gemm_kernel(const float* __restrict__ A, int lda,
                                                   const float* __restrict__ Bm, int ldb,
                                                   float* __restrict__ C, int ldc,
                                                   int M, int N, int K) {
  __shared__ float As[16][65];
  __shared__ float Bs[16][64];
  int tid = threadIdx.x;
  int tx = tid & 15, ty = tid >> 4;
  int row0 = blockIdx.y * 64, col0 = blockIdx.x * 64;
  float acc[4][4] = {};
  for (int k0 = 0; k0 < K; k0 += 16) {
    {
      int c = tid & 15, r4 = tid >> 4;
#pragma unroll
      for (int j = 0; j < 4; ++j) {
        int r = r4 + j * 16;
        float v = 0.f;
        if (k0 + c < K) v = A[(size_t)(row0 + r) * lda + k0 + c];
        As[c][r] = v;
      }
    }
    {
      int n = tid & 63, c4 = tid >> 6;
#pragma unroll
      for (int j = 0; j < 4; ++j) {
        int c = c4 + j * 4;
        float v = 0.f;
        if (k0 + c < K) v = Bm[(size_t)(k0 + c) * ldb + col0 + n];
        Bs[c][n] = v;
      }
    }
    __syncthreads();
#pragma unroll
    for (int kk = 0; kk < 16; ++kk) {
      float a[4], b[4];
#pragma unroll
      for (int i = 0; i < 4; ++i) a[i] = As[kk][ty * 4 + i];
#pragma unroll
      for (int j = 0; j < 4; ++j) b[j] = Bs[kk][tx * 4 + j];
#pragma unroll
      for (int i = 0; i < 4; ++i)
#pragma unroll
        for (int j = 0; j < 4; ++j) acc[i][j] += a[i] * b[j];
    }
    __syncthreads();
  }
#pragma unroll
  for (int i = 0; i < 4; ++i)
#pragma unroll
    for (int j = 0; j < 4; ++j)
      C[(size_t)(row0 + ty * 4 + i) * ldc + col0 + tx * 4 + j] = acc[i][j];
}

// ---------------- neg-dist via split-bf16 MFMA, 128x128 tile, LDS-transposed coalesced store ----
// D[n][m] = 2*x_n.x_m - xx_n - xx_m. A-operand = n-rows, B-operand = m-rows.
__global__ __launch_bounds__(256) void mfma_dist_kernel(const float* __restrict__ X, int ldx, int C,
                                                        const float* __restrict__ xx, float* __restrict__ D,
                                                        int b0, int N) {
  extern __shared__ char smem[];
  ushort* Nhi = (ushort*)smem;              // [128][40]
  ushort* Nlo = Nhi + 128 * 40;
  ushort* Mhi = Nlo + 128 * 40;
  ushort* Mlo = Mhi + 128 * 40;
  float* outT = (float*)smem;               // [128][128], aliases staging after last K-iter

  int batch = b0 + blockIdx.z;
  const float* Xb = X + (size_t)batch * N * ldx;
  const float* xxb = xx + (size_t)batch * N;
  float* Db = D + (size_t)blockIdx.z * N * N;
  const int tid = threadIdx.x;
  const int lane = tid & 63, w = tid >> 6;
  const int wn = w & 1, wm = w >> 1;
  const int m0 = blockIdx.x * 128, n0 = blockIdx.y * 128;
  f32x4 acc[4][4] = {};

  int kt = (C + 31) / 32;
  for (int k0i = 0; k0i < kt; ++k0i) {
    int k0 = k0i * 32;
    if (k0i) __syncthreads();
#pragma unroll
    for (int e = 0; e < 4; ++e) {
      int flat = tid + e * 256;        // 0..1023 float4 units over [128 r][32 c]
      int r = flat >> 3, c4 = (flat & 7) * 4;
      float4 vn, vm;
      if ((C & 31) == 0) {
        vn = *(const float4*)(Xb + (size_t)(n0 + r) * ldx + k0 + c4);
        vm = *(const float4*)(Xb + (size_t)(m0 + r) * ldx + k0 + c4);
      } else {
        float tn[4], tm[4];
        for (int q = 0; q < 4; ++q) {
          int kc = k0 + c4 + q;
          tn[q] = (kc < C) ? Xb[(size_t)(n0 + r) * ldx + kc] : 0.f;
          tm[q] = (kc < C) ? Xb[(size_t)(m0 + r) * ldx + kc] : 0.f;
        }
        vn.x = tn[0]; vn.y = tn[1]; vn.z = tn[2]; vn.w = tn[3];
        vm.x = tm[0]; vm.y = tm[1]; vm.z = tm[2]; vm.w = tm[3];
      }
      ushort4 h, l;
      bsplit(vn.x, h.x, l.x); bsplit(vn.y, h.y, l.y);
      bsplit(vn.z, h.z, l.z); bsplit(vn.w, h.w, l.w);
      *(ushort4*)&Nhi[r * 40 + c4] = h;
      *(ushort4*)&Nlo[r * 40 + c4] = l;
      bsplit(vm.x, h.x, l.x); bsplit(vm.y, h.y, l.y);
      bsplit(vm.z, h.z, l.z); bsplit(vm.w, h.w, l.w);
      *(ushort4*)&Mhi[r * 40 + c4] = h;
      *(ushort4*)&Mlo[r * 40 + c4] = l;
    }
    __syncthreads();
    short8v nh[4], nl[4], mh[4], ml[4];
    int kg = (lane >> 4) * 8;
    int lr = lane & 15;
#pragma unroll
    for (int i = 0; i < 4; ++i) {
      nh[i] = *(const short8v*)&Nhi[(wn * 64 + i * 16 + lr) * 40 + kg];
      nl[i] = *(const short8v*)&Nlo[(wn * 64 + i * 16 + lr) * 40 + kg];
      mh[i] = *(const short8v*)&Mhi[(wm * 64 + i * 16 + lr) * 40 + kg];
      ml[i] = *(const short8v*)&Mlo[(wm * 64 + i * 16 + lr) * 40 + kg];
    }
#pragma unroll
    for (int i = 0; i < 4; ++i)
#pragma unroll
      for (int j = 0; j < 4; ++j) {
        acc[i][j] = __builtin_amdgcn_mfma_f32_16x16x32_bf16(nh[i], mh[j], acc[i][j], 0, 0, 0);
        acc[i][j] = __builtin_amdgcn_mfma_f32_16x16x32_bf16(nh[i], ml[j], acc[i][j], 0, 0, 0);
        acc[i][j] = __builtin_amdgcn_mfma_f32_16x16x32_bf16(nl[i], mh[j], acc[i][j], 0, 0, 0);
      }
    __syncthreads();
  }

  // epilogue: 2*acc - xx_n - xx_m into LDS tile, then coalesced float4 stores
  int fq = lane >> 4, fr = lane & 15;
  float xmv[4];
#pragma unroll
  for (int j = 0; j < 4; ++j) xmv[j] = xxb[m0 + wm * 64 + j * 16 + fr];
#pragma unroll
  for (int i = 0; i < 4; ++i) {
#pragma unroll
    for (int r = 0; r < 4; ++r) {
      int nl_ = wn * 64 + i * 16 + fq * 4 + r;
      float xn = xxb[n0 + nl_];
#pragma unroll
      for (int j = 0; j < 4; ++j) {
        int ml_ = wm * 64 + j * 16 + fr;
        outT[nl_ * 128 + ml_] = 2.f * acc[i][j][r] - xn - xmv[j];
      }
    }
  }
  __syncthreads();
#pragma unroll
  for (int v = 0; v < 16; ++v) {
    int row = v * 8 + (tid >> 5);
    int col = (tid & 31) * 4;
    *(float4*)(Db + (size_t)(n0 + row) * N + m0 + col) = *(float4*)&outT[row * 128 + col];
  }
}

// ---------------- top-K via MSB radix select (set semantics; exact lax.top_k tie-break) ----------------
__global__ __launch_bounds__(256) void topk_kernel(const float* __restrict__ D, int* __restrict__ idxo,
                                                   int b0, int N, int Ktop) {
  int n = blockIdx.x;
  int bz = blockIdx.y;
  const float* row = D + (size_t)bz * N * N + (size_t)n * N;
  int tid = threadIdx.x;

  unsigned u[8];
#pragma unroll
  for (int j = 0; j < 8; ++j) {
    float d = row[j * 256 + tid];
    unsigned x = __float_as_uint(d);
    u[j] = (x & 0x80000000u) ? ~x : (x | 0x80000000u);
  }

  __shared__ unsigned h4[4][256];
  __shared__ unsigned binc[256];
  __shared__ unsigned sufs[256];
  __shared__ unsigned sel[3];
  __shared__ int cnt_g, eqn;
  __shared__ int eqlist[2048];

  unsigned prefix = 0, Tmask = 0;
  int krem = Ktop;
  bool done = false;
  unsigned* myh = h4[tid >> 6];

  for (int lev = 0; lev < 4 && !done; ++lev) {
    int shift = 24 - lev * 8;
    h4[0][tid] = 0; h4[1][tid] = 0; h4[2][tid] = 0; h4[3][tid] = 0;
    __syncthreads();
    unsigned pmask = Tmask;
#pragma unroll
    for (int j = 0; j < 8; ++j)
      if ((u[j] & pmask) == prefix) atomicAdd(&myh[(u[j] >> shift) & 255], 1u);
    __syncthreads();
    unsigned c = h4[0][tid] + h4[1][tid] + h4[2][tid] + h4[3][tid];
    binc[tid] = c; sufs[tid] = c;
    __syncthreads();
    for (int st = 1; st < 256; st <<= 1) {
      unsigned add = (tid + st < 256) ? sufs[tid + st] : 0u;
      __syncthreads();
      sufs[tid] += add;
      __syncthreads();
    }
    unsigned above = sufs[tid] - binc[tid];
    if (above < (unsigned)krem && (unsigned)krem <= sufs[tid]) {
      sel[0] = (unsigned)tid; sel[1] = (unsigned)krem - above; sel[2] = binc[tid];
    }
    __syncthreads();
    prefix |= sel[0] << shift;
    krem = (int)sel[1];
    Tmask = 0xFFFFFFFFu << shift;
    done = (sel[2] == (unsigned)krem);
    __syncthreads();
  }

  if (tid == 0) { cnt_g = 0; eqn = 0; }
  __syncthreads();
  int* out = idxo + ((size_t)(b0 + bz) * N + n) * Ktop;
#pragma unroll
  for (int j = 0; j < 8; ++j) {
    int m = j * 256 + tid;
    unsigned um = u[j] & Tmask;
    if (um > prefix) {
      out[atomicAdd(&cnt_g, 1)] = m;
    } else if (um == prefix) {
      eqlist[atomicAdd(&eqn, 1)] = m;
    }
  }
  __syncthreads();
  int cg = cnt_g, ne = eqn, ke = krem;
  if (ne == ke) {
    if (tid < ne) out[cg + tid] = eqlist[tid];
  } else if (tid == 0) {
    int last = -1;
    for (int s = 0; s < ke; ++s) {
      int mn = 0x7FFFFFFF;
      for (int i2 = 0; i2 < ne; ++i2) {
        int v = eqlist[i2];
        if (v > last && v < mn) mn = v;
      }
      out[cg + s] = mn; last = mn;
    }
  }
}

// ---------------- gather + max over K + scale/bias/leaky (float4) ----------------
__global__ __launch_bounds__(256) void gathermax_kernel(const float* __restrict__ YZ, int ldyz, int cout,
                                                        const int* __restrict__ idxo,
                                                        const float* __restrict__ g, const float* __restrict__ bias,
                                                        float* __restrict__ outp, int ldo, int N, int Ktop,
                                                        int total4) {
  int t = blockIdx.x * 256 + threadIdx.x;
  if (t >= total4) return;
  int cq = cout >> 2;
  int dq = t % cq, bn = t / cq;
  int d0 = dq * 4;
  int b = bn / N;
  const int* ip = idxo + (size_t)bn * Ktop;
  float4 gv = *(const float4*)(g + d0);
  float4 bv = *(const float4*)(bias + d0);
  float4 zv = *(const float4*)(YZ + (size_t)bn * ldyz + cout + d0);
  bool px = gv.x >= 0.f, py = gv.y >= 0.f, pz = gv.z >= 0.f, pw = gv.w >= 0.f;
  float4 best;
  best.x = px ? -FLT_MAX : FLT_MAX;
  best.y = py ? -FLT_MAX : FLT_MAX;
  best.z = pz ? -FLT_MAX : FLT_MAX;
  best.w = pw ? -FLT_MAX : FLT_MAX;
  for (int k = 0; k < Ktop; ++k) {
    int m = ip[k];
    float4 y = *(const float4*)(YZ + ((size_t)b * N + m) * ldyz + d0);
    best.x = px ? fmaxf(best.x, y.x) : fminf(best.x, y.x);
    best.y = py ? fmaxf(best.y, y.y) : fminf(best.y, y.y);
    best.z = pz ? fmaxf(best.z, y.z) : fminf(best.z, y.z);
    best.w = pw ? fmaxf(best.w, y.w) : fminf(best.w, y.w);
  }
  float4 o;
  float h;
  h = (best.x + zv.x) * gv.x + bv.x; o.x = h >= 0.f ? h : NSLOPE * h;
  h = (best.y + zv.y) * gv.y + bv.y; o.y = h >= 0.f ? h : NSLOPE * h;
  h = (best.z + zv.z) * gv.z + bv.z; o.z = h >= 0.f ? h : NSLOPE * h;
  h = (best.w + zv.w) * gv.w + bv.w; o.w = h >= 0.f ? h : NSLOPE * h;
  *(float4*)(outp + (size_t)bn * ldo + d0) = o;
}

// ---------------- final GEMM via split-bf16 MFMA, fused fp32->hi/lo staging ----------------
__global__ __launch_bounds__(256) void mfma_out_kernel(const float* __restrict__ XC,
                                                       const float* __restrict__ W,
                                                       const float* __restrict__ g,
                                                       const float* __restrict__ bias,
                                                       float* __restrict__ outp) {
  __shared__ ushort Ws_hi[128 * 40];
  __shared__ ushort Ws_lo[128 * 40];
  __shared__ ushort Xs_hi[128 * 40];
  __shared__ ushort Xs_lo[128 * 40];
  const int tid = threadIdx.x;
  const int lane = tid & 63, w = tid >> 6;
  const int wd = w & 1, wn = w >> 1;
  const int col0 = blockIdx.x * 128;  // d
  const int row0 = blockIdx.y * 128;  // m
  f32x4 acc[4][4] = {};

  for (int k0 = 0; k0 < 512; k0 += 32) {
#pragma unroll
    for (int e = 0; e < 4; ++e) {
      int flat = tid + e * 256;
      int r = flat >> 3;
      int c4 = (flat & 7) * 4;
      float4 v = *(const float4*)(XC + (size_t)(row0 + r) * 512 + k0 + c4);
      ushort4 h, l;
      bsplit(v.x, h.x, l.x); bsplit(v.y, h.y, l.y);
      bsplit(v.z, h.z, l.z); bsplit(v.w, h.w, l.w);
      *(ushort4*)&Xs_hi[r * 40 + c4] = h;
      *(ushort4*)&Xs_lo[r * 40 + c4] = l;
    }
#pragma unroll
    for (int e = 0; e < 4; ++e) {
      int flat = tid + e * 256;
      int k = (flat >> 6) * 2;
      int c2 = (flat & 63) * 2;
      float2 v0 = *(const float2*)(W + (size_t)(k0 + k) * 1024 + col0 + c2);
      float2 v1 = *(const float2*)(W + (size_t)(k0 + k + 1) * 1024 + col0 + c2);
      ushort h00, h01, h10, h11, l00, l01, l10, l11;
      bsplit(v0.x, h00, l00); bsplit(v0.y, h01, l01);
      bsplit(v1.x, h10, l10); bsplit(v1.y, h11, l11);
      *(uint*)&Ws_hi[c2 * 40 + k]       = (uint)h00 | ((uint)h10 << 16);
      *(uint*)&Ws_hi[(c2 + 1) * 40 + k] = (uint)h01 | ((uint)h11 << 16);
      *(uint*)&Ws_lo[c2 * 40 + k]       = (uint)l00 | ((uint)l10 << 16);
      *(uint*)&Ws_lo[(c2 + 1) * 40 + k] = (uint)l01 | ((uint)l11 << 16);
    }
    __syncthreads();
    short8v wh[4], wl[4], xh[4], xl[4];
    int kg = (lane >> 4) * 8;
    int lr = lane & 15;
#pragma unroll
    for (int i = 0; i < 4; ++i) {
      wh[i] = *(const short8v*)&Ws_hi[(wd * 64 + i * 16 + lr) * 40 + kg];
      wl[i] = *(const short8v*)&Ws_lo[(wd * 64 + i * 16 + lr) * 40 + kg];
      xh[i] = *(const short8v*)&Xs_hi[(wn * 64 + i * 16 + lr) * 40 + kg];
      xl[i] = *(const short8v*)&Xs_lo[(wn * 64 + i * 16 + lr) * 40 + kg];
    }
#pragma unroll
    for (int i = 0; i < 4; ++i)
#pragma unroll
      for (int j = 0; j < 4; ++j) {
        acc[i][j] = __builtin_amdgcn_mfma_f32_16x16x32_bf16(wh[i], xh[j], acc[i][j], 0, 0, 0);
        acc[i][j] = __builtin_amdgcn_mfma_f32_16x16x32_bf16(wh[i], xl[j], acc[i][j], 0, 0, 0);
        acc[i][j] = __builtin_amdgcn_mfma_f32_16x16x32_bf16(wl[i], xh[j], acc[i][j], 0, 0, 0);
      }
    __syncthreads();
  }
  int fq = lane >> 4, fr = lane & 15;
#pragma unroll
  for (int i = 0; i < 4; ++i) {
#pragma unroll
    for (int r = 0; r < 4; ++r) {
      int d = col0 + wd * 64 + i * 16 + fq * 4 + r;
      float gv = g[d], bv = bias[d];
#pragma unroll
      for (int j = 0; j < 4; ++j) {
        int mrow = row0 + wn * 64 + j * 16 + fr;
        int batch = mrow >> 11, n = mrow & 2047;
        float h = acc[i][j][r] * gv + bv;
        h = h >= 0.f ? h : NSLOPE * h;
        outp[(((size_t)batch << 10) + d) * 2048 + n] = h;
      }
    }
  }
}

extern "C" void kernel_launch(void* const* d_in, const int* in_sizes, int n_in,
                              void* d_out, int out_size, void* d_ws, size_t ws_size,
                              hipStream_t stream) {
  const int B = 8, N = 2048, Ktop = 20;
  const int M = B * N;  // 16384

  const float* pts = (const float*)d_in[0];
  const float* W1 = (const float*)d_in[1];  const float* g1 = (const float*)d_in[2];  const float* b1 = (const float*)d_in[3];
  const float* W2 = (const float*)d_in[4];  const float* g2 = (const float*)d_in[5];  const float* b2 = (const float*)d_in[6];
  const float* W3 = (const float*)d_in[7];  const float* g3 = (const float*)d_in[8];  const float* b3 = (const float*)d_in[9];
  const float* W4 = (const float*)d_in[10]; const float* g4 = (const float*)d_in[11]; const float* b4 = (const float*)d_in[12];
  const float* W5 = (const float*)d_in[13]; const float* g5 = (const float*)d_in[14]; const float* b5 = (const float*)d_in[15];

  float* p = (float*)d_ws;
  float* XC = p;  p += (size_t)M * 512;        // concat feature buffer [x1|x2|x3|x4]
  float* Wc = p;  p += 128 * 512;              // combined weight, max cin*2cout
  float* xx = p;  p += M;                      // per-point sum of squares
  int* idxb = (int*)p; p = (float*)(idxb + (size_t)M * Ktop);
  float* shared = p;                           // D / YZ overlap (disjoint lifetimes)
  size_t shared_bytes = ws_size - (size_t)((char*)shared - (char*)d_ws);
  float* D = shared;
  float* YZ = shared;
  int chunk = (int)(shared_bytes / ((size_t)N * N * sizeof(float)));
  if (chunk > B) chunk = B;
  if (chunk < 1) chunk = 1;

  auto knn = [&](const float* Xp, int ldx, int C) {
    sumsq_kernel<<<(M + 255) / 256, 256, 0, stream>>>(Xp, ldx, C, xx, M);
    for (int b0 = 0; b0 < B; b0 += chunk) {
      int nb = (B - b0 < chunk) ? (B - b0) : chunk;
      mfma_dist_kernel<<<dim3(N / 128, N / 128, nb), 256, 65536, stream>>>(Xp, ldx, C, xx, D, b0, N);
      topk_kernel<<<dim3(N, nb), 256, 0, stream>>>(D, idxb, b0, N, Ktop);
    }
  };

  auto econv = [&](const float* Xp, int ldx, int cin, int cout,
                   const float* W, const float* g, const float* bb, float* outp) {
    int tot = cin * 2 * cout;
    wcprep_kernel<<<(tot + 255) / 256, 256, 0, stream>>>(W, cin, cout, Wc);
    gemm_kernel<<<dim3(2 * cout / 64, M / 64), 256, 0, stream>>>(Xp, ldx, Wc, 2 * cout, YZ, 2 * cout, M, 2 * cout, cin);
    int total4 = B * N * (cout / 4);
    gathermax_kernel<<<(total4 + 255) / 256, 256, 0, stream>>>(YZ, 2 * cout, cout, idxb, g, bb, outp, 512, N, Ktop, total4);
  };

  knn(pts, 3, 3);
  econv(pts, 3, 3, 64, W1, g1, b1, XC + 0);
  knn(XC + 0, 512, 64);
  econv(XC + 0, 512, 64, 64, W2, g2, b2, XC + 64);
  knn(XC + 64, 512, 64);
  econv(XC + 64, 512, 64, 128, W3, g3, b3, XC + 128);
  knn(XC + 128, 512, 128);
  econv(XC + 128, 512, 128, 256, W4, g4, b4, XC + 256);

  // final: fused split-bf16 MFMA GEMM (no extra ws buffers)
  mfma_out_kernel<<<dim3(1024 / 128, M / 128), 256, 0, stream>>>(XC, W5, g5, b5, (float*)d_out);
}

// Round 11
// 921.680 us; speedup vs baseline: 2.3082x; 1.0545x over previous
//
#include <hip/hip_runtime.h>
#include <hip/hip_bf16.h>
#include <float.h>

#define NSLOPE 0.2f

typedef __attribute__((ext_vector_type(8))) short short8v;
typedef __attribute__((ext_vector_type(4))) float f32x4;

__device__ inline void bsplit(float v, ushort& h, ushort& l) {
  __hip_bfloat16 hb = __float2bfloat16(v);
  float hf = __bfloat162float(hb);
  __hip_bfloat16 lb = __float2bfloat16(v - hf);
  h = *(ushort*)&hb; l = *(ushort*)&lb;
}

// ---------------- sum of squares per point ----------------
__global__ __launch_bounds__(256) void sumsq_kernel(const float* __restrict__ X, int ldx, int C,
                                                    float* __restrict__ xx, int total) {
  int t = blockIdx.x * 256 + threadIdx.x;
  if (t >= total) return;
  const float* p = X + (size_t)t * ldx;
  float s = 0.f;
  for (int c = 0; c < C; ++c) { float v = p[c]; s += v * v; }
  xx[t] = s;
}

// ---------------- combined-weight prep ----------------
__global__ __launch_bounds__(256) void wcprep_kernel(const float* __restrict__ W, int cin, int cout,
                                                     float* __restrict__ Wc) {
  int t = blockIdx.x * 256 + threadIdx.x;
  int tot = cin * 2 * cout;
  if (t >= tot) return;
  int c = t / (2 * cout), j = t % (2 * cout);
  float v;
  if (j < cout) v = W[c * cout + j];
  else          v = W[(cin + c) * cout + (j - cout)] - W[c * cout + (j - cout)];
  Wc[t] = v;
}

// ---------------- generic fp32 GEMM (small econv gemms) ----------------
__global__ __launch_bounds__(256) void gemm_kernel(const float* __restrict__ A, int lda,
                                                   const float* __restrict__ Bm, int ldb,
                                                   float* __restrict__ C, int ldc,
                                                   int M, int N, int K) {
  __shared__ float As[16][65];
  __shared__ float Bs[16][64];
  int tid = threadIdx.x;
  int tx = tid & 15, ty = tid >> 4;
  int row0 = blockIdx.y * 64, col0 = blockIdx.x * 64;
  float acc[4][4] = {};
  for (int k0 = 0; k0 < K; k0 += 16) {
    {
      int c = tid & 15, r4 = tid >> 4;
#pragma unroll
      for (int j = 0; j < 4; ++j) {
        int r = r4 + j * 16;
        float v = 0.f;
        if (k0 + c < K) v = A[(size_t)(row0 + r) * lda + k0 + c];
        As[c][r] = v;
      }
    }
    {
      int n = tid & 63, c4 = tid >> 6;
#pragma unroll
      for (int j = 0; j < 4; ++j) {
        int c = c4 + j * 4;
        float v = 0.f;
        if (k0 + c < K) v = Bm[(size_t)(k0 + c) * ldb + col0 + n];
        Bs[c][n] = v;
      }
    }
    __syncthreads();
#pragma unroll
    for (int kk = 0; kk < 16; ++kk) {
      float a[4], b[4];
#pragma unroll
      for (int i = 0; i < 4; ++i) a[i] = As[kk][ty * 4 + i];
#pragma unroll
      for (int j = 0; j < 4; ++j) b[j] = Bs[kk][tx * 4 + j];
#pragma unroll
      for (int i = 0; i < 4; ++i)
#pragma unroll
        for (int j = 0; j < 4; ++j) acc[i][j] += a[i] * b[j];
    }
    __syncthreads();
  }
#pragma unroll
  for (int i = 0; i < 4; ++i)
#pragma unroll
    for (int j = 0; j < 4; ++j)
      C[(size_t)(row0 + ty * 4 + i) * ldc + col0 + tx * 4 + j] = acc[i][j];
}

// ---------------- neg-dist via split-bf16 MFMA, 128x128 tile, LDS-transposed coalesced store ----
__global__ __launch_bounds__(256) void mfma_dist_kernel(const float* __restrict__ X, int ldx, int C,
                                                        const float* __restrict__ xx, float* __restrict__ D,
                                                        int b0, int N) {
  extern __shared__ char smem[];
  ushort* Nhi = (ushort*)smem;              // [128][40]
  ushort* Nlo = Nhi + 128 * 40;
  ushort* Mhi = Nlo + 128 * 40;
  ushort* Mlo = Mhi + 128 * 40;
  float* outT = (float*)smem;               // [128][128], aliases staging after last K-iter

  int batch = b0 + blockIdx.z;
  const float* Xb = X + (size_t)batch * N * ldx;
  const float* xxb = xx + (size_t)batch * N;
  float* Db = D + (size_t)blockIdx.z * N * N;
  const int tid = threadIdx.x;
  const int lane = tid & 63, w = tid >> 6;
  const int wn = w & 1, wm = w >> 1;
  const int m0 = blockIdx.x * 128, n0 = blockIdx.y * 128;
  f32x4 acc[4][4] = {};

  int kt = (C + 31) / 32;
  for (int k0i = 0; k0i < kt; ++k0i) {
    int k0 = k0i * 32;
    if (k0i) __syncthreads();
#pragma unroll
    for (int e = 0; e < 4; ++e) {
      int flat = tid + e * 256;
      int r = flat >> 3, c4 = (flat & 7) * 4;
      float4 vn, vm;
      if ((C & 31) == 0) {
        vn = *(const float4*)(Xb + (size_t)(n0 + r) * ldx + k0 + c4);
        vm = *(const float4*)(Xb + (size_t)(m0 + r) * ldx + k0 + c4);
      } else {
        float tn[4], tm[4];
        for (int q = 0; q < 4; ++q) {
          int kc = k0 + c4 + q;
          tn[q] = (kc < C) ? Xb[(size_t)(n0 + r) * ldx + kc] : 0.f;
          tm[q] = (kc < C) ? Xb[(size_t)(m0 + r) * ldx + kc] : 0.f;
        }
        vn.x = tn[0]; vn.y = tn[1]; vn.z = tn[2]; vn.w = tn[3];
        vm.x = tm[0]; vm.y = tm[1]; vm.z = tm[2]; vm.w = tm[3];
      }
      ushort4 h, l;
      bsplit(vn.x, h.x, l.x); bsplit(vn.y, h.y, l.y);
      bsplit(vn.z, h.z, l.z); bsplit(vn.w, h.w, l.w);
      *(ushort4*)&Nhi[r * 40 + c4] = h;
      *(ushort4*)&Nlo[r * 40 + c4] = l;
      bsplit(vm.x, h.x, l.x); bsplit(vm.y, h.y, l.y);
      bsplit(vm.z, h.z, l.z); bsplit(vm.w, h.w, l.w);
      *(ushort4*)&Mhi[r * 40 + c4] = h;
      *(ushort4*)&Mlo[r * 40 + c4] = l;
    }
    __syncthreads();
    short8v nh[4], nl[4], mh[4], ml[4];
    int kg = (lane >> 4) * 8;
    int lr = lane & 15;
#pragma unroll
    for (int i = 0; i < 4; ++i) {
      nh[i] = *(const short8v*)&Nhi[(wn * 64 + i * 16 + lr) * 40 + kg];
      nl[i] = *(const short8v*)&Nlo[(wn * 64 + i * 16 + lr) * 40 + kg];
      mh[i] = *(const short8v*)&Mhi[(wm * 64 + i * 16 + lr) * 40 + kg];
      ml[i] = *(const short8v*)&Mlo[(wm * 64 + i * 16 + lr) * 40 + kg];
    }
#pragma unroll
    for (int i = 0; i < 4; ++i)
#pragma unroll
      for (int j = 0; j < 4; ++j) {
        acc[i][j] = __builtin_amdgcn_mfma_f32_16x16x32_bf16(nh[i], mh[j], acc[i][j], 0, 0, 0);
        acc[i][j] = __builtin_amdgcn_mfma_f32_16x16x32_bf16(nh[i], ml[j], acc[i][j], 0, 0, 0);
        acc[i][j] = __builtin_amdgcn_mfma_f32_16x16x32_bf16(nl[i], mh[j], acc[i][j], 0, 0, 0);
      }
    __syncthreads();
  }

  int fq = lane >> 4, fr = lane & 15;
  float xmv[4];
#pragma unroll
  for (int j = 0; j < 4; ++j) xmv[j] = xxb[m0 + wm * 64 + j * 16 + fr];
#pragma unroll
  for (int i = 0; i < 4; ++i) {
#pragma unroll
    for (int r = 0; r < 4; ++r) {
      int nl_ = wn * 64 + i * 16 + fq * 4 + r;
      float xn = xxb[n0 + nl_];
#pragma unroll
      for (int j = 0; j < 4; ++j) {
        int ml_ = wm * 64 + j * 16 + fr;
        outT[nl_ * 128 + ml_] = 2.f * acc[i][j][r] - xn - xmv[j];
      }
    }
  }
  __syncthreads();
#pragma unroll
  for (int v = 0; v < 16; ++v) {
    int row = v * 8 + (tid >> 5);
    int col = (tid & 31) * 4;
    *(float4*)(Db + (size_t)(n0 + row) * N + m0 + col) = *(float4*)&outT[row * 128 + col];
  }
}

// ---------------- top-K: fixed 2-level radix select, wave-scan, rank-select finish ----------------
// Exact lax.top_k SET (consumer is permutation-invariant; ties -> lowest index).
__global__ __launch_bounds__(256) void topk_kernel(const float* __restrict__ D, int* __restrict__ idxo,
                                                   int b0, int N, int Ktop) {
  int n = blockIdx.x;
  int bz = blockIdx.y;
  const float* row = D + (size_t)bz * N * N + (size_t)n * N;
  int tid = threadIdx.x;
  int lane = tid & 63, wv = tid >> 6;

  unsigned u[8];
#pragma unroll
  for (int j = 0; j < 8; ++j) {
    float d = row[j * 256 + tid];
    unsigned x = __float_as_uint(d);
    u[j] = (x & 0x80000000u) ? ~x : (x | 0x80000000u);
  }

  __shared__ unsigned h4[4][256];
  __shared__ unsigned wsum[4];
  __shared__ unsigned sel[2];
  __shared__ int cnt_g, eqn;
  __shared__ unsigned long long eq[1024];

  unsigned* myh = h4[wv];
  h4[0][tid] = 0; h4[1][tid] = 0; h4[2][tid] = 0; h4[3][tid] = 0;
  if (tid == 0) { cnt_g = 0; eqn = 0; }
  __syncthreads();                                     // B1

  // ---- level 0: top 8 bits ----
#pragma unroll
  for (int j = 0; j < 8; ++j) atomicAdd(&myh[u[j] >> 24], 1u);
  __syncthreads();                                     // B2
  unsigned ke = (unsigned)Ktop;
  {
    unsigned c = h4[0][tid] + h4[1][tid] + h4[2][tid] + h4[3][tid];
    unsigned s = c;
#pragma unroll
    for (int off = 1; off < 64; off <<= 1) {
      unsigned o = __shfl_down(s, off, 64);
      if (lane + off < 64) s += o;
    }
    if (lane == 0) wsum[wv] = s;
    __syncthreads();                                   // B3
    unsigned add = 0;
    for (int g = wv + 1; g < 4; ++g) add += wsum[g];
    unsigned suf = s + add;
    unsigned above = suf - c;
    if (above < ke && ke <= suf) { sel[0] = (unsigned)tid; sel[1] = ke - above; }
    h4[0][tid] = 0; h4[1][tid] = 0; h4[2][tid] = 0; h4[3][tid] = 0;
  }
  __syncthreads();                                     // B4
  unsigned bbin = sel[0];
  ke = sel[1];

  // ---- level 1: bits 16..23 among boundary-bin candidates ----
#pragma unroll
  for (int j = 0; j < 8; ++j)
    if ((u[j] >> 24) == bbin) atomicAdd(&myh[(u[j] >> 16) & 255], 1u);
  __syncthreads();                                     // B5
  {
    unsigned c = h4[0][tid] + h4[1][tid] + h4[2][tid] + h4[3][tid];
    unsigned s = c;
#pragma unroll
    for (int off = 1; off < 64; off <<= 1) {
      unsigned o = __shfl_down(s, off, 64);
      if (lane + off < 64) s += o;
    }
    if (lane == 0) wsum[wv] = s;
    __syncthreads();                                   // B6
    unsigned add = 0;
    for (int g = wv + 1; g < 4; ++g) add += wsum[g];
    unsigned suf = s + add;
    unsigned above = suf - c;
    if (above < ke && ke <= suf) { sel[0] = (unsigned)tid; sel[1] = ke - above; }
  }
  __syncthreads();                                     // B7
  unsigned full = (bbin << 8) | sel[0];                // 16-bit boundary prefix
  unsigned kf = sel[1];

  // ---- classification on 16-bit prefix ----
  int* out = idxo + ((size_t)(b0 + bz) * N + n) * Ktop;
#pragma unroll
  for (int j = 0; j < 8; ++j) {
    int m = j * 256 + tid;
    unsigned p = u[j] >> 16;
    if (p > full) {
      out[atomicAdd(&cnt_g, 1)] = m;
    } else if (p == full) {
      int e = atomicAdd(&eqn, 1);
      if (e < 1024) eq[e] = ((unsigned long long)u[j] << 32) | (unsigned)(N - 1 - m);
    }
  }
  __syncthreads();                                     // B8
  int ne = eqn, cg = cnt_g;
  if (ne <= 1024) {
    // exact rank-select: keys distinct (index packed) -> exactly kf selected
    for (int i = tid; i < ne; i += 256) {
      unsigned long long me = eq[i];
      int rank = 0;
      for (int j2 = 0; j2 < ne; ++j2) rank += (eq[j2] > me) ? 1 : 0;
      if (rank < (int)kf) out[atomicAdd(&cnt_g, 1)] = N - 1 - (int)(unsigned)(me & 0xFFFFFFFFu);
    }
  } else if (tid == 0) {
    // degenerate fallback: serial exact select among prefix-equal elements
    unsigned long long last = ~0ull;
    for (int s2 = 0; s2 < (int)kf; ++s2) {
      unsigned long long best = 0;
      for (int mm = 0; mm < N; ++mm) {
        float d2 = row[mm];
        unsigned x = __float_as_uint(d2);
        x = (x & 0x80000000u) ? ~x : (x | 0x80000000u);
        if ((x >> 16) != full) continue;
        unsigned long long key = ((unsigned long long)x << 32) | (unsigned)(N - 1 - mm);
        if (key < last && key > best) best = key;
      }
      out[cg + s2] = N - 1 - (int)(unsigned)(best & 0xFFFFFFFFu);
      last = best;
    }
  }
}

// ---------------- gather + max over K + scale/bias/leaky (float4) ----------------
__global__ __launch_bounds__(256) void gathermax_kernel(const float* __restrict__ YZ, int ldyz, int cout,
                                                        const int* __restrict__ idxo,
                                                        const float* __restrict__ g, const float* __restrict__ bias,
                                                        float* __restrict__ outp, int ldo, int N, int Ktop,
                                                        int total4) {
  int t = blockIdx.x * 256 + threadIdx.x;
  if (t >= total4) return;
  int cq = cout >> 2;
  int dq = t % cq, bn = t / cq;
  int d0 = dq * 4;
  int b = bn / N;
  const int* ip = idxo + (size_t)bn * Ktop;
  float4 gv = *(const float4*)(g + d0);
  float4 bv = *(const float4*)(bias + d0);
  float4 zv = *(const float4*)(YZ + (size_t)bn * ldyz + cout + d0);
  bool px = gv.x >= 0.f, py = gv.y >= 0.f, pz = gv.z >= 0.f, pw = gv.w >= 0.f;
  float4 best;
  best.x = px ? -FLT_MAX : FLT_MAX;
  best.y = py ? -FLT_MAX : FLT_MAX;
  best.z = pz ? -FLT_MAX : FLT_MAX;
  best.w = pw ? -FLT_MAX : FLT_MAX;
  for (int k = 0; k < Ktop; ++k) {
    int m = ip[k];
    float4 y = *(const float4*)(YZ + ((size_t)b * N + m) * ldyz + d0);
    best.x = px ? fmaxf(best.x, y.x) : fminf(best.x, y.x);
    best.y = py ? fmaxf(best.y, y.y) : fminf(best.y, y.y);
    best.z = pz ? fmaxf(best.z, y.z) : fminf(best.z, y.z);
    best.w = pw ? fmaxf(best.w, y.w) : fminf(best.w, y.w);
  }
  float4 o;
  float h;
  h = (best.x + zv.x) * gv.x + bv.x; o.x = h >= 0.f ? h : NSLOPE * h;
  h = (best.y + zv.y) * gv.y + bv.y; o.y = h >= 0.f ? h : NSLOPE * h;
  h = (best.z + zv.z) * gv.z + bv.z; o.z = h >= 0.f ? h : NSLOPE * h;
  h = (best.w + zv.w) * gv.w + bv.w; o.w = h >= 0.f ? h : NSLOPE * h;
  *(float4*)(outp + (size_t)bn * ldo + d0) = o;
}

// ---------------- final GEMM via split-bf16 MFMA, fused fp32->hi/lo staging ----------------
__global__ __launch_bounds__(256) void mfma_out_kernel(const float* __restrict__ XC,
                                                       const float* __restrict__ W,
                                                       const float* __restrict__ g,
                                                       const float* __restrict__ bias,
                                                       float* __restrict__ outp) {
  __shared__ ushort Ws_hi[128 * 40];
  __shared__ ushort Ws_lo[128 * 40];
  __shared__ ushort Xs_hi[128 * 40];
  __shared__ ushort Xs_lo[128 * 40];
  const int tid = threadIdx.x;
  const int lane = tid & 63, w = tid >> 6;
  const int wd = w & 1, wn = w >> 1;
  const int col0 = blockIdx.x * 128;  // d
  const int row0 = blockIdx.y * 128;  // m
  f32x4 acc[4][4] = {};

  for (int k0 = 0; k0 < 512; k0 += 32) {
#pragma unroll
    for (int e = 0; e < 4; ++e) {
      int flat = tid + e * 256;
      int r = flat >> 3;
      int c4 = (flat & 7) * 4;
      float4 v = *(const float4*)(XC + (size_t)(row0 + r) * 512 + k0 + c4);
      ushort4 h, l;
      bsplit(v.x, h.x, l.x); bsplit(v.y, h.y, l.y);
      bsplit(v.z, h.z, l.z); bsplit(v.w, h.w, l.w);
      *(ushort4*)&Xs_hi[r * 40 + c4] = h;
      *(ushort4*)&Xs_lo[r * 40 + c4] = l;
    }
#pragma unroll
    for (int e = 0; e < 4; ++e) {
      int flat = tid + e * 256;
      int k = (flat >> 6) * 2;
      int c2 = (flat & 63) * 2;
      float2 v0 = *(const float2*)(W + (size_t)(k0 + k) * 1024 + col0 + c2);
      float2 v1 = *(const float2*)(W + (size_t)(k0 + k + 1) * 1024 + col0 + c2);
      ushort h00, h01, h10, h11, l00, l01, l10, l11;
      bsplit(v0.x, h00, l00); bsplit(v0.y, h01, l01);
      bsplit(v1.x, h10, l10); bsplit(v1.y, h11, l11);
      *(uint*)&Ws_hi[c2 * 40 + k]       = (uint)h00 | ((uint)h10 << 16);
      *(uint*)&Ws_hi[(c2 + 1) * 40 + k] = (uint)h01 | ((uint)h11 << 16);
      *(uint*)&Ws_lo[c2 * 40 + k]       = (uint)l00 | ((uint)l10 << 16);
      *(uint*)&Ws_lo[(c2 + 1) * 40 + k] = (uint)l01 | ((uint)l11 << 16);
    }
    __syncthreads();
    short8v wh[4], wl[4], xh[4], xl[4];
    int kg = (lane >> 4) * 8;
    int lr = lane & 15;
#pragma unroll
    for (int i = 0; i < 4; ++i) {
      wh[i] = *(const short8v*)&Ws_hi[(wd * 64 + i * 16 + lr) * 40 + kg];
      wl[i] = *(const short8v*)&Ws_lo[(wd * 64 + i * 16 + lr) * 40 + kg];
      xh[i] = *(const short8v*)&Xs_hi[(wn * 64 + i * 16 + lr) * 40 + kg];
      xl[i] = *(const short8v*)&Xs_lo[(wn * 64 + i * 16 + lr) * 40 + kg];
    }
#pragma unroll
    for (int i = 0; i < 4; ++i)
#pragma unroll
      for (int j = 0; j < 4; ++j) {
        acc[i][j] = __builtin_amdgcn_mfma_f32_16x16x32_bf16(wh[i], xh[j], acc[i][j], 0, 0, 0);
        acc[i][j] = __builtin_amdgcn_mfma_f32_16x16x32_bf16(wh[i], xl[j], acc[i][j], 0, 0, 0);
        acc[i][j] = __builtin_amdgcn_mfma_f32_16x16x32_bf16(wl[i], xh[j], acc[i][j], 0, 0, 0);
      }
    __syncthreads();
  }
  int fq = lane >> 4, fr = lane & 15;
#pragma unroll
  for (int i = 0; i < 4; ++i) {
#pragma unroll
    for (int r = 0; r < 4; ++r) {
      int d = col0 + wd * 64 + i * 16 + fq * 4 + r;
      float gv = g[d], bv = bias[d];
#pragma unroll
      for (int j = 0; j < 4; ++j) {
        int mrow = row0 + wn * 64 + j * 16 + fr;
        int batch = mrow >> 11, n = mrow & 2047;
        float h = acc[i][j][r] * gv + bv;
        h = h >= 0.f ? h : NSLOPE * h;
        outp[(((size_t)batch << 10) + d) * 2048 + n] = h;
      }
    }
  }
}

extern "C" void kernel_launch(void* const* d_in, const int* in_sizes, int n_in,
                              void* d_out, int out_size, void* d_ws, size_t ws_size,
                              hipStream_t stream) {
  const int B = 8, N = 2048, Ktop = 20;
  const int M = B * N;  // 16384

  const float* pts = (const float*)d_in[0];
  const float* W1 = (const float*)d_in[1];  const float* g1 = (const float*)d_in[2];  const float* b1 = (const float*)d_in[3];
  const float* W2 = (const float*)d_in[4];  const float* g2 = (const float*)d_in[5];  const float* b2 = (const float*)d_in[6];
  const float* W3 = (const float*)d_in[7];  const float* g3 = (const float*)d_in[8];  const float* b3 = (const float*)d_in[9];
  const float* W4 = (const float*)d_in[10]; const float* g4 = (const float*)d_in[11]; const float* b4 = (const float*)d_in[12];
  const float* W5 = (const float*)d_in[13]; const float* g5 = (const float*)d_in[14]; const float* b5 = (const float*)d_in[15];

  float* p = (float*)d_ws;
  float* XC = p;  p += (size_t)M * 512;        // concat feature buffer [x1|x2|x3|x4]
  float* Wc = p;  p += 128 * 512;              // combined weight, max cin*2cout
  float* xx = p;  p += M;                      // per-point sum of squares
  int* idxb = (int*)p; p = (float*)(idxb + (size_t)M * Ktop);
  float* shared = p;                           // D / YZ overlap (disjoint lifetimes)
  size_t shared_bytes = ws_size - (size_t)((char*)shared - (char*)d_ws);
  float* D = shared;
  float* YZ = shared;
  int chunk = (int)(shared_bytes / ((size_t)N * N * sizeof(float)));
  if (chunk > B) chunk = B;
  if (chunk < 1) chunk = 1;

  auto knn = [&](const float* Xp, int ldx, int C) {
    sumsq_kernel<<<(M + 255) / 256, 256, 0, stream>>>(Xp, ldx, C, xx, M);
    for (int b0 = 0; b0 < B; b0 += chunk) {
      int nb = (B - b0 < chunk) ? (B - b0) : chunk;
      mfma_dist_kernel<<<dim3(N / 128, N / 128, nb), 256, 65536, stream>>>(Xp, ldx, C, xx, D, b0, N);
      topk_kernel<<<dim3(N, nb), 256, 0, stream>>>(D, idxb, b0, N, Ktop);
    }
  };

  auto econv = [&](const float* Xp, int ldx, int cin, int cout,
                   const float* W, const float* g, const float* bb, float* outp) {
    int tot = cin * 2 * cout;
    wcprep_kernel<<<(tot + 255) / 256, 256, 0, stream>>>(W, cin, cout, Wc);
    gemm_kernel<<<dim3(2 * cout / 64, M / 64), 256, 0, stream>>>(Xp, ldx, Wc, 2 * cout, YZ, 2 * cout, M, 2 * cout, cin);
    int total4 = B * N * (cout / 4);
    gathermax_kernel<<<(total4 + 255) / 256, 256, 0, stream>>>(YZ, 2 * cout, cout, idxb, g, bb, outp, 512, N, Ktop, total4);
  };

  knn(pts, 3, 3);
  econv(pts, 3, 3, 64, W1, g1, b1, XC + 0);
  knn(XC + 0, 512, 64);
  econv(XC + 0, 512, 64, 64, W2, g2, b2, XC + 64);
  knn(XC + 64, 512, 64);
  econv(XC + 64, 512, 64, 128, W3, g3, b3, XC + 128);
  knn(XC + 128, 512, 128);
  econv(XC + 128, 512, 128, 256, W4, g4, b4, XC + 256);

  // final: fused split-bf16 MFMA GEMM (no extra ws buffers)
  mfma_out_kernel<<<dim3(1024 / 128, M / 128), 256, 0, stream>>>(XC, W5, g5, b5, (float*)d_out);
}

// Round 12
// 746.850 us; speedup vs baseline: 2.8485x; 1.2341x over previous
//
#include <hip/hip_runtime.h>
#include <hip/hip_bf16.h>
#include <float.h>

#define NSLOPE 0.2f

typedef __attribute__((ext_vector_type(8))) short short8v;
typedef __attribute__((ext_vector_type(4))) float f32x4;

__device__ inline void bsplit(float v, ushort& h, ushort& l) {
  __hip_bfloat16 hb = __float2bfloat16(v);
  float hf = __bfloat162float(hb);
  __hip_bfloat16 lb = __float2bfloat16(v - hf);
  h = *(ushort*)&hb; l = *(ushort*)&lb;
}

// ---------------- sum of squares per point ----------------
__global__ __launch_bounds__(256) void sumsq_kernel(const float* __restrict__ X, int ldx, int C,
                                                    float* __restrict__ xx, int total) {
  int t = blockIdx.x * 256 + threadIdx.x;
  if (t >= total) return;
  const float* p = X + (size_t)t * ldx;
  float s = 0.f;
  for (int c = 0; c < C; ++c) { float v = p[c]; s += v * v; }
  xx[t] = s;
}

// ---------------- combined-weight prep ----------------
__global__ __launch_bounds__(256) void wcprep_kernel(const float* __restrict__ W, int cin, int cout,
                                                     float* __restrict__ Wc) {
  int t = blockIdx.x * 256 + threadIdx.x;
  int tot = cin * 2 * cout;
  if (t >= tot) return;
  int c = t / (2 * cout), j = t % (2 * cout);
  float v;
  if (j < cout) v = W[c * cout + j];
  else          v = W[(cin + c) * cout + (j - cout)] - W[c * cout + (j - cout)];
  Wc[t] = v;
}

// ---------------- generic fp32 GEMM (small econv gemms) ----------------
__global__ __launch_bounds__(256) void gemm_kernel(const float* __restrict__ A, int lda,
                                                   const float* __restrict__ Bm, int ldb,
                                                   float* __restrict__ C, int ldc,
                                                   int M, int N, int K) {
  __shared__ float As[16][65];
  __shared__ float Bs[16][64];
  int tid = threadIdx.x;
  int tx = tid & 15, ty = tid >> 4;
  int row0 = blockIdx.y * 64, col0 = blockIdx.x * 64;
  float acc[4][4] = {};
  for (int k0 = 0; k0 < K; k0 += 16) {
    {
      int c = tid & 15, r4 = tid >> 4;
#pragma unroll
      for (int j = 0; j < 4; ++j) {
        int r = r4 + j * 16;
        float v = 0.f;
        if (k0 + c < K) v = A[(size_t)(row0 + r) * lda + k0 + c];
        As[c][r] = v;
      }
    }
    {
      int n = tid & 63, c4 = tid >> 6;
#pragma unroll
      for (int j = 0; j < 4; ++j) {
        int c = c4 + j * 4;
        float v = 0.f;
        if (k0 + c < K) v = Bm[(size_t)(k0 + c) * ldb + col0 + n];
        Bs[c][n] = v;
      }
    }
    __syncthreads();
#pragma unroll
    for (int kk = 0; kk < 16; ++kk) {
      float a[4], b[4];
#pragma unroll
      for (int i = 0; i < 4; ++i) a[i] = As[kk][ty * 4 + i];
#pragma unroll
      for (int j = 0; j < 4; ++j) b[j] = Bs[kk][tx * 4 + j];
#pragma unroll
      for (int i = 0; i < 4; ++i)
#pragma unroll
        for (int j = 0; j < 4; ++j) acc[i][j] += a[i] * b[j];
    }
    __syncthreads();
  }
#pragma unroll
  for (int i = 0; i < 4; ++i)
#pragma unroll
    for (int j = 0; j < 4; ++j)
      C[(size_t)(row0 + ty * 4 + i) * ldc + col0 + tx * 4 + j] = acc[i][j];
}

// ---------------- neg-dist via split-bf16 MFMA, 128x128 tile, LDS-transposed coalesced store ----
__global__ __launch_bounds__(256) void mfma_dist_kernel(const float* __restrict__ X, int ldx, int C,
                                                        const float* __restrict__ xx, float* __restrict__ D,
                                                        int b0, int N) {
  extern __shared__ char smem[];
  ushort* Nhi = (ushort*)smem;              // [128][40]
  ushort* Nlo = Nhi + 128 * 40;
  ushort* Mhi = Nlo + 128 * 40;
  ushort* Mlo = Mhi + 128 * 40;
  float* outT = (float*)smem;               // [128][128], aliases staging after last K-iter

  int batch = b0 + blockIdx.z;
  const float* Xb = X + (size_t)batch * N * ldx;
  const float* xxb = xx + (size_t)batch * N;
  float* Db = D + (size_t)blockIdx.z * N * N;
  const int tid = threadIdx.x;
  const int lane = tid & 63, w = tid >> 6;
  const int wn = w & 1, wm = w >> 1;
  const int m0 = blockIdx.x * 128, n0 = blockIdx.y * 128;
  f32x4 acc[4][4] = {};

  int kt = (C + 31) / 32;
  for (int k0i = 0; k0i < kt; ++k0i) {
    int k0 = k0i * 32;
    if (k0i) __syncthreads();
#pragma unroll
    for (int e = 0; e < 4; ++e) {
      int flat = tid + e * 256;
      int r = flat >> 3, c4 = (flat & 7) * 4;
      float4 vn, vm;
      if ((C & 31) == 0) {
        vn = *(const float4*)(Xb + (size_t)(n0 + r) * ldx + k0 + c4);
        vm = *(const float4*)(Xb + (size_t)(m0 + r) * ldx + k0 + c4);
      } else {
        float tn[4], tm[4];
        for (int q = 0; q < 4; ++q) {
          int kc = k0 + c4 + q;
          tn[q] = (kc < C) ? Xb[(size_t)(n0 + r) * ldx + kc] : 0.f;
          tm[q] = (kc < C) ? Xb[(size_t)(m0 + r) * ldx + kc] : 0.f;
        }
        vn.x = tn[0]; vn.y = tn[1]; vn.z = tn[2]; vn.w = tn[3];
        vm.x = tm[0]; vm.y = tm[1]; vm.z = tm[2]; vm.w = tm[3];
      }
      ushort4 h, l;
      bsplit(vn.x, h.x, l.x); bsplit(vn.y, h.y, l.y);
      bsplit(vn.z, h.z, l.z); bsplit(vn.w, h.w, l.w);
      *(ushort4*)&Nhi[r * 40 + c4] = h;
      *(ushort4*)&Nlo[r * 40 + c4] = l;
      bsplit(vm.x, h.x, l.x); bsplit(vm.y, h.y, l.y);
      bsplit(vm.z, h.z, l.z); bsplit(vm.w, h.w, l.w);
      *(ushort4*)&Mhi[r * 40 + c4] = h;
      *(ushort4*)&Mlo[r * 40 + c4] = l;
    }
    __syncthreads();
    short8v nh[4], nl[4], mh[4], ml[4];
    int kg = (lane >> 4) * 8;
    int lr = lane & 15;
#pragma unroll
    for (int i = 0; i < 4; ++i) {
      nh[i] = *(const short8v*)&Nhi[(wn * 64 + i * 16 + lr) * 40 + kg];
      nl[i] = *(const short8v*)&Nlo[(wn * 64 + i * 16 + lr) * 40 + kg];
      mh[i] = *(const short8v*)&Mhi[(wm * 64 + i * 16 + lr) * 40 + kg];
      ml[i] = *(const short8v*)&Mlo[(wm * 64 + i * 16 + lr) * 40 + kg];
    }
#pragma unroll
    for (int i = 0; i < 4; ++i)
#pragma unroll
      for (int j = 0; j < 4; ++j) {
        acc[i][j] = __builtin_amdgcn_mfma_f32_16x16x32_bf16(nh[i], mh[j], acc[i][j], 0, 0, 0);
        acc[i][j] = __builtin_amdgcn_mfma_f32_16x16x32_bf16(nh[i], ml[j], acc[i][j], 0, 0, 0);
        acc[i][j] = __builtin_amdgcn_mfma_f32_16x16x32_bf16(nl[i], mh[j], acc[i][j], 0, 0, 0);
      }
    __syncthreads();
  }

  int fq = lane >> 4, fr = lane & 15;
  float xmv[4];
#pragma unroll
  for (int j = 0; j < 4; ++j) xmv[j] = xxb[m0 + wm * 64 + j * 16 + fr];
#pragma unroll
  for (int i = 0; i < 4; ++i) {
#pragma unroll
    for (int r = 0; r < 4; ++r) {
      int nl_ = wn * 64 + i * 16 + fq * 4 + r;
      float xn = xxb[n0 + nl_];
#pragma unroll
      for (int j = 0; j < 4; ++j) {
        int ml_ = wm * 64 + j * 16 + fr;
        outT[nl_ * 128 + ml_] = 2.f * acc[i][j][r] - xn - xmv[j];
      }
    }
  }
  __syncthreads();
#pragma unroll
  for (int v = 0; v < 16; ++v) {
    int row = v * 8 + (tid >> 5);
    int col = (tid & 31) * 4;
    *(float4*)(Db + (size_t)(n0 + row) * N + m0 + col) = *(float4*)&outT[row * 128 + col];
  }
}

// ---------------- top-K: 1 wave per row, bitwise radix-select, no LDS / no barriers ----------------
// Exact lax.top_k SET (consumer is permutation-invariant; ties -> lowest index).
__global__ __launch_bounds__(256) void topk_kernel(const float* __restrict__ D, int* __restrict__ idxo,
                                                   int b0, int N, int Ktop) {
  int lane = threadIdx.x & 63, wv = threadIdx.x >> 6;
  int n = blockIdx.x * 4 + wv;
  int bz = blockIdx.y;
  const float* row = D + (size_t)bz * N * N + (size_t)n * N;

  // 32 values per lane; value index m = (j>>2)*256 + lane*4 + (j&3)
  unsigned u[32];
#pragma unroll
  for (int g = 0; g < 8; ++g) {
    float4 v = *(const float4*)(row + g * 256 + lane * 4);
    unsigned x;
    x = __float_as_uint(v.x); u[g * 4 + 0] = (x & 0x80000000u) ? ~x : (x | 0x80000000u);
    x = __float_as_uint(v.y); u[g * 4 + 1] = (x & 0x80000000u) ? ~x : (x | 0x80000000u);
    x = __float_as_uint(v.z); u[g * 4 + 2] = (x & 0x80000000u) ? ~x : (x | 0x80000000u);
    x = __float_as_uint(v.w); u[g * 4 + 3] = (x & 0x80000000u) ? ~x : (x | 0x80000000u);
  }

  const unsigned K = (unsigned)Ktop;
  unsigned prefix = 0;
  bool exact = false;
#pragma unroll 1
  for (int b = 31; b >= 0; --b) {
    unsigned cand = prefix | (1u << b);
    int c = 0;
#pragma unroll
    for (int j = 0; j < 32; ++j) c += (u[j] >= cand) ? 1 : 0;
#pragma unroll
    for (int off = 32; off >= 1; off >>= 1) c += __shfl_xor(c, off, 64);
    if ((unsigned)c >= K) {
      prefix = cand;
      if ((unsigned)c == K) { exact = true; break; }
    }
  }

  int* out = idxo + ((size_t)(b0 + bz) * N + n) * Ktop;
  int base = 0;
#pragma unroll
  for (int j = 0; j < 32; ++j) {
    bool s = exact ? (u[j] >= prefix) : (u[j] > prefix);
    unsigned long long mask = __ballot(s);
    if (s) {
      int pos = base + (int)__popcll(mask & ((1ull << lane) - 1ull));
      out[pos] = (j >> 2) * 256 + lane * 4 + (j & 3);
    }
    base += (int)__popcll(mask);
  }
  if (!exact) {
    // ties at the exact k-th value: pick smallest indices (lax.top_k tie-break)
    int kf = (int)K - base;
    int last = -1;
    for (int s2 = 0; s2 < kf; ++s2) {
      int local = 0x7FFFFFFF;
#pragma unroll
      for (int j = 0; j < 32; ++j)
        if (u[j] == prefix) {
          int m = (j >> 2) * 256 + lane * 4 + (j & 3);
          if (m > last && m < local) local = m;
        }
#pragma unroll
      for (int off = 32; off >= 1; off >>= 1) {
        int o = __shfl_xor(local, off, 64);
        local = o < local ? o : local;
      }
      if (lane == 0) out[base + s2] = local;
      last = local;
    }
  }
}

// ---------------- gather + max over K + scale/bias/leaky (float4) ----------------
__global__ __launch_bounds__(256) void gathermax_kernel(const float* __restrict__ YZ, int ldyz, int cout,
                                                        const int* __restrict__ idxo,
                                                        const float* __restrict__ g, const float* __restrict__ bias,
                                                        float* __restrict__ outp, int ldo, int N, int Ktop,
                                                        int total4) {
  int t = blockIdx.x * 256 + threadIdx.x;
  if (t >= total4) return;
  int cq = cout >> 2;
  int dq = t % cq, bn = t / cq;
  int d0 = dq * 4;
  int b = bn / N;
  const int* ip = idxo + (size_t)bn * Ktop;
  float4 gv = *(const float4*)(g + d0);
  float4 bv = *(const float4*)(bias + d0);
  float4 zv = *(const float4*)(YZ + (size_t)bn * ldyz + cout + d0);
  bool px = gv.x >= 0.f, py = gv.y >= 0.f, pz = gv.z >= 0.f, pw = gv.w >= 0.f;
  float4 best;
  best.x = px ? -FLT_MAX : FLT_MAX;
  best.y = py ? -FLT_MAX : FLT_MAX;
  best.z = pz ? -FLT_MAX : FLT_MAX;
  best.w = pw ? -FLT_MAX : FLT_MAX;
  for (int k = 0; k < Ktop; ++k) {
    int m = ip[k];
    float4 y = *(const float4*)(YZ + ((size_t)b * N + m) * ldyz + d0);
    best.x = px ? fmaxf(best.x, y.x) : fminf(best.x, y.x);
    best.y = py ? fmaxf(best.y, y.y) : fminf(best.y, y.y);
    best.z = pz ? fmaxf(best.z, y.z) : fminf(best.z, y.z);
    best.w = pw ? fmaxf(best.w, y.w) : fminf(best.w, y.w);
  }
  float4 o;
  float h;
  h = (best.x + zv.x) * gv.x + bv.x; o.x = h >= 0.f ? h : NSLOPE * h;
  h = (best.y + zv.y) * gv.y + bv.y; o.y = h >= 0.f ? h : NSLOPE * h;
  h = (best.z + zv.z) * gv.z + bv.z; o.z = h >= 0.f ? h : NSLOPE * h;
  h = (best.w + zv.w) * gv.w + bv.w; o.w = h >= 0.f ? h : NSLOPE * h;
  *(float4*)(outp + (size_t)bn * ldo + d0) = o;
}

// ---------------- final GEMM via split-bf16 MFMA, fused fp32->hi/lo staging ----------------
__global__ __launch_bounds__(256) void mfma_out_kernel(const float* __restrict__ XC,
                                                       const float* __restrict__ W,
                                                       const float* __restrict__ g,
                                                       const float* __restrict__ bias,
                                                       float* __restrict__ outp) {
  __shared__ ushort Ws_hi[128 * 40];
  __shared__ ushort Ws_lo[128 * 40];
  __shared__ ushort Xs_hi[128 * 40];
  __shared__ ushort Xs_lo[128 * 40];
  const int tid = threadIdx.x;
  const int lane = tid & 63, w = tid >> 6;
  const int wd = w & 1, wn = w >> 1;
  const int col0 = blockIdx.x * 128;  // d
  const int row0 = blockIdx.y * 128;  // m
  f32x4 acc[4][4] = {};

  for (int k0 = 0; k0 < 512; k0 += 32) {
#pragma unroll
    for (int e = 0; e < 4; ++e) {
      int flat = tid + e * 256;
      int r = flat >> 3;
      int c4 = (flat & 7) * 4;
      float4 v = *(const float4*)(XC + (size_t)(row0 + r) * 512 + k0 + c4);
      ushort4 h, l;
      bsplit(v.x, h.x, l.x); bsplit(v.y, h.y, l.y);
      bsplit(v.z, h.z, l.z); bsplit(v.w, h.w, l.w);
      *(ushort4*)&Xs_hi[r * 40 + c4] = h;
      *(ushort4*)&Xs_lo[r * 40 + c4] = l;
    }
#pragma unroll
    for (int e = 0; e < 4; ++e) {
      int flat = tid + e * 256;
      int k = (flat >> 6) * 2;
      int c2 = (flat & 63) * 2;
      float2 v0 = *(const float2*)(W + (size_t)(k0 + k) * 1024 + col0 + c2);
      float2 v1 = *(const float2*)(W + (size_t)(k0 + k + 1) * 1024 + col0 + c2);
      ushort h00, h01, h10, h11, l00, l01, l10, l11;
      bsplit(v0.x, h00, l00); bsplit(v0.y, h01, l01);
      bsplit(v1.x, h10, l10); bsplit(v1.y, h11, l11);
      *(uint*)&Ws_hi[c2 * 40 + k]       = (uint)h00 | ((uint)h10 << 16);
      *(uint*)&Ws_hi[(c2 + 1) * 40 + k] = (uint)h01 | ((uint)h11 << 16);
      *(uint*)&Ws_lo[c2 * 40 + k]       = (uint)l00 | ((uint)l10 << 16);
      *(uint*)&Ws_lo[(c2 + 1) * 40 + k] = (uint)l01 | ((uint)l11 << 16);
    }
    __syncthreads();
    short8v wh[4], wl[4], xh[4], xl[4];
    int kg = (lane >> 4) * 8;
    int lr = lane & 15;
#pragma unroll
    for (int i = 0; i < 4; ++i) {
      wh[i] = *(const short8v*)&Ws_hi[(wd * 64 + i * 16 + lr) * 40 + kg];
      wl[i] = *(const short8v*)&Ws_lo[(wd * 64 + i * 16 + lr) * 40 + kg];
      xh[i] = *(const short8v*)&Xs_hi[(wn * 64 + i * 16 + lr) * 40 + kg];
      xl[i] = *(const short8v*)&Xs_lo[(wn * 64 + i * 16 + lr) * 40 + kg];
    }
#pragma unroll
    for (int i = 0; i < 4; ++i)
#pragma unroll
      for (int j = 0; j < 4; ++j) {
        acc[i][j] = __builtin_amdgcn_mfma_f32_16x16x32_bf16(wh[i], xh[j], acc[i][j], 0, 0, 0);
        acc[i][j] = __builtin_amdgcn_mfma_f32_16x16x32_bf16(wh[i], xl[j], acc[i][j], 0, 0, 0);
        acc[i][j] = __builtin_amdgcn_mfma_f32_16x16x32_bf16(wl[i], xh[j], acc[i][j], 0, 0, 0);
      }
    __syncthreads();
  }
  int fq = lane >> 4, fr = lane & 15;
#pragma unroll
  for (int i = 0; i < 4; ++i) {
#pragma unroll
    for (int r = 0; r < 4; ++r) {
      int d = col0 + wd * 64 + i * 16 + fq * 4 + r;
      float gv = g[d], bv = bias[d];
#pragma unroll
      for (int j = 0; j < 4; ++j) {
        int mrow = row0 + wn * 64 + j * 16 + fr;
        int batch = mrow >> 11, n = mrow & 2047;
        float h = acc[i][j][r] * gv + bv;
        h = h >= 0.f ? h : NSLOPE * h;
        outp[(((size_t)batch << 10) + d) * 2048 + n] = h;
      }
    }
  }
}

extern "C" void kernel_launch(void* const* d_in, const int* in_sizes, int n_in,
                              void* d_out, int out_size, void* d_ws, size_t ws_size,
                              hipStream_t stream) {
  const int B = 8, N = 2048, Ktop = 20;
  const int M = B * N;  // 16384

  const float* pts = (const float*)d_in[0];
  const float* W1 = (const float*)d_in[1];  const float* g1 = (const float*)d_in[2];  const float* b1 = (const float*)d_in[3];
  const float* W2 = (const float*)d_in[4];  const float* g2 = (const float*)d_in[5];  const float* b2 = (const float*)d_in[6];
  const float* W3 = (const float*)d_in[7];  const float* g3 = (const float*)d_in[8];  const float* b3 = (const float*)d_in[9];
  const float* W4 = (const float*)d_in[10]; const float* g4 = (const float*)d_in[11]; const float* b4 = (const float*)d_in[12];
  const float* W5 = (const float*)d_in[13]; const float* g5 = (const float*)d_in[14]; const float* b5 = (const float*)d_in[15];

  float* p = (float*)d_ws;
  float* XC = p;  p += (size_t)M * 512;        // concat feature buffer [x1|x2|x3|x4]
  float* Wc = p;  p += 128 * 512;              // combined weight, max cin*2cout
  float* xx = p;  p += M;                      // per-point sum of squares
  int* idxb = (int*)p; p = (float*)(idxb + (size_t)M * Ktop);
  float* shared = p;                           // D / YZ overlap (disjoint lifetimes)
  size_t shared_bytes = ws_size - (size_t)((char*)shared - (char*)d_ws);
  float* D = shared;
  float* YZ = shared;
  int chunk = (int)(shared_bytes / ((size_t)N * N * sizeof(float)));
  if (chunk > B) chunk = B;
  if (chunk < 1) chunk = 1;

  auto knn = [&](const float* Xp, int ldx, int C) {
    sumsq_kernel<<<(M + 255) / 256, 256, 0, stream>>>(Xp, ldx, C, xx, M);
    for (int b0 = 0; b0 < B; b0 += chunk) {
      int nb = (B - b0 < chunk) ? (B - b0) : chunk;
      mfma_dist_kernel<<<dim3(N / 128, N / 128, nb), 256, 65536, stream>>>(Xp, ldx, C, xx, D, b0, N);
      topk_kernel<<<dim3(N / 4, nb), 256, 0, stream>>>(D, idxb, b0, N, Ktop);
    }
  };

  auto econv = [&](const float* Xp, int ldx, int cin, int cout,
                   const float* W, const float* g, const float* bb, float* outp) {
    int tot = cin * 2 * cout;
    wcprep_kernel<<<(tot + 255) / 256, 256, 0, stream>>>(W, cin, cout, Wc);
    gemm_kernel<<<dim3(2 * cout / 64, M / 64), 256, 0, stream>>>(Xp, ldx, Wc, 2 * cout, YZ, 2 * cout, M, 2 * cout, cin);
    int total4 = B * N * (cout / 4);
    gathermax_kernel<<<(total4 + 255) / 256, 256, 0, stream>>>(YZ, 2 * cout, cout, idxb, g, bb, outp, 512, N, Ktop, total4);
  };

  knn(pts, 3, 3);
  econv(pts, 3, 3, 64, W1, g1, b1, XC + 0);
  knn(XC + 0, 512, 64);
  econv(XC + 0, 512, 64, 64, W2, g2, b2, XC + 64);
  knn(XC + 64, 512, 64);
  econv(XC + 64, 512, 64, 128, W3, g3, b3, XC + 128);
  knn(XC + 128, 512, 128);
  econv(XC + 128, 512, 128, 256, W4, g4, b4, XC + 256);

  // final: fused split-bf16 MFMA GEMM (no extra ws buffers)
  mfma_out_kernel<<<dim3(1024 / 128, M / 128), 256, 0, stream>>>(XC, W5, g5, b5, (float*)d_out);
}

// Round 13
// 741.823 us; speedup vs baseline: 2.8678x; 1.0068x over previous
//
#include <hip/hip_runtime.h>
#include <hip/hip_bf16.h>
#include <float.h>

#define NSLOPE 0.2f

typedef __attribute__((ext_vector_type(8))) short short8v;
typedef __attribute__((ext_vector_type(4))) float f32x4;

__device__ inline void bsplit(float v, ushort& h, ushort& l) {
  __hip_bfloat16 hb = __float2bfloat16(v);
  float hf = __bfloat162float(hb);
  __hip_bfloat16 lb = __float2bfloat16(v - hf);
  h = *(ushort*)&hb; l = *(ushort*)&lb;
}

// ---------------- sum of squares per point ----------------
__global__ __launch_bounds__(256) void sumsq_kernel(const float* __restrict__ X, int ldx, int C,
                                                    float* __restrict__ xx, int total) {
  int t = blockIdx.x * 256 + threadIdx.x;
  if (t >= total) return;
  const float* p = X + (size_t)t * ldx;
  float s = 0.f;
  for (int c = 0; c < C; ++c) { float v = p[c]; s += v * v; }
  xx[t] = s;
}

// ---------------- combined-weight prep ----------------
__global__ __launch_bounds__(256) void wcprep_kernel(const float* __restrict__ W, int cin, int cout,
                                                     float* __restrict__ Wc) {
  int t = blockIdx.x * 256 + threadIdx.x;
  int tot = cin * 2 * cout;
  if (t >= tot) return;
  int c = t / (2 * cout), j = t % (2 * cout);
  float v;
  if (j < cout) v = W[c * cout + j];
  else          v = W[(cin + c) * cout + (j - cout)] - W[c * cout + (j - cout)];
  Wc[t] = v;
}

// ---------------- generic fp32 GEMM (small econv gemms) ----------------
__global__ __launch_bounds__(256) void gemm_kernel(const float* __restrict__ A, int lda,
                                                   const float* __restrict__ Bm, int ldb,
                                                   float* __restrict__ C, int ldc,
                                                   int M, int N, int K) {
  __shared__ float As[16][65];
  __shared__ float Bs[16][64];
  int tid = threadIdx.x;
  int tx = tid & 15, ty = tid >> 4;
  int row0 = blockIdx.y * 64, col0 = blockIdx.x * 64;
  float acc[4][4] = {};
  for (int k0 = 0; k0 < K; k0 += 16) {
    {
      int c = tid & 15, r4 = tid >> 4;
#pragma unroll
      for (int j = 0; j < 4; ++j) {
        int r = r4 + j * 16;
        float v = 0.f;
        if (k0 + c < K) v = A[(size_t)(row0 + r) * lda + k0 + c];
        As[c][r] = v;
      }
    }
    {
      int n = tid & 63, c4 = tid >> 6;
#pragma unroll
      for (int j = 0; j < 4; ++j) {
        int c = c4 + j * 4;
        float v = 0.f;
        if (k0 + c < K) v = Bm[(size_t)(k0 + c) * ldb + col0 + n];
        Bs[c][n] = v;
      }
    }
    __syncthreads();
#pragma unroll
    for (int kk = 0; kk < 16; ++kk) {
      float a[4], b[4];
#pragma unroll
      for (int i = 0; i < 4; ++i) a[i] = As[kk][ty * 4 + i];
#pragma unroll
      for (int j = 0; j < 4; ++j) b[j] = Bs[kk][tx * 4 + j];
#pragma unroll
      for (int i = 0; i < 4; ++i)
#pragma unroll
        for (int j = 0; j < 4; ++j) acc[i][j] += a[i] * b[j];
    }
    __syncthreads();
  }
#pragma unroll
  for (int i = 0; i < 4; ++i)
#pragma unroll
    for (int j = 0; j < 4; ++j)
      C[(size_t)(row0 + ty * 4 + i) * ldc + col0 + tx * 4 + j] = acc[i][j];
}

// ---------------- neg-dist via split-bf16 MFMA, 128x128 tile, LDS-transposed coalesced store ----
__global__ __launch_bounds__(256) void mfma_dist_kernel(const float* __restrict__ X, int ldx, int C,
                                                        const float* __restrict__ xx, float* __restrict__ D,
                                                        int b0, int N) {
  extern __shared__ char smem[];
  ushort* Nhi = (ushort*)smem;              // [128][40]
  ushort* Nlo = Nhi + 128 * 40;
  ushort* Mhi = Nlo + 128 * 40;
  ushort* Mlo = Mhi + 128 * 40;
  float* outT = (float*)smem;               // [128][128], aliases staging after last K-iter

  int batch = b0 + blockIdx.z;
  const float* Xb = X + (size_t)batch * N * ldx;
  const float* xxb = xx + (size_t)batch * N;
  float* Db = D + (size_t)blockIdx.z * N * N;
  const int tid = threadIdx.x;
  const int lane = tid & 63, w = tid >> 6;
  const int wn = w & 1, wm = w >> 1;
  const int m0 = blockIdx.x * 128, n0 = blockIdx.y * 128;
  f32x4 acc[4][4] = {};

  int kt = (C + 31) / 32;
  for (int k0i = 0; k0i < kt; ++k0i) {
    int k0 = k0i * 32;
    if (k0i) __syncthreads();
#pragma unroll
    for (int e = 0; e < 4; ++e) {
      int flat = tid + e * 256;
      int r = flat >> 3, c4 = (flat & 7) * 4;
      float4 vn, vm;
      if ((C & 31) == 0) {
        vn = *(const float4*)(Xb + (size_t)(n0 + r) * ldx + k0 + c4);
        vm = *(const float4*)(Xb + (size_t)(m0 + r) * ldx + k0 + c4);
      } else {
        float tn[4], tm[4];
        for (int q = 0; q < 4; ++q) {
          int kc = k0 + c4 + q;
          tn[q] = (kc < C) ? Xb[(size_t)(n0 + r) * ldx + kc] : 0.f;
          tm[q] = (kc < C) ? Xb[(size_t)(m0 + r) * ldx + kc] : 0.f;
        }
        vn.x = tn[0]; vn.y = tn[1]; vn.z = tn[2]; vn.w = tn[3];
        vm.x = tm[0]; vm.y = tm[1]; vm.z = tm[2]; vm.w = tm[3];
      }
      ushort4 h, l;
      bsplit(vn.x, h.x, l.x); bsplit(vn.y, h.y, l.y);
      bsplit(vn.z, h.z, l.z); bsplit(vn.w, h.w, l.w);
      *(ushort4*)&Nhi[r * 40 + c4] = h;
      *(ushort4*)&Nlo[r * 40 + c4] = l;
      bsplit(vm.x, h.x, l.x); bsplit(vm.y, h.y, l.y);
      bsplit(vm.z, h.z, l.z); bsplit(vm.w, h.w, l.w);
      *(ushort4*)&Mhi[r * 40 + c4] = h;
      *(ushort4*)&Mlo[r * 40 + c4] = l;
    }
    __syncthreads();
    short8v nh[4], nl[4], mh[4], ml[4];
    int kg = (lane >> 4) * 8;
    int lr = lane & 15;
#pragma unroll
    for (int i = 0; i < 4; ++i) {
      nh[i] = *(const short8v*)&Nhi[(wn * 64 + i * 16 + lr) * 40 + kg];
      nl[i] = *(const short8v*)&Nlo[(wn * 64 + i * 16 + lr) * 40 + kg];
      mh[i] = *(const short8v*)&Mhi[(wm * 64 + i * 16 + lr) * 40 + kg];
      ml[i] = *(const short8v*)&Mlo[(wm * 64 + i * 16 + lr) * 40 + kg];
    }
#pragma unroll
    for (int i = 0; i < 4; ++i)
#pragma unroll
      for (int j = 0; j < 4; ++j) {
        acc[i][j] = __builtin_amdgcn_mfma_f32_16x16x32_bf16(nh[i], mh[j], acc[i][j], 0, 0, 0);
        acc[i][j] = __builtin_amdgcn_mfma_f32_16x16x32_bf16(nh[i], ml[j], acc[i][j], 0, 0, 0);
        acc[i][j] = __builtin_amdgcn_mfma_f32_16x16x32_bf16(nl[i], mh[j], acc[i][j], 0, 0, 0);
      }
    __syncthreads();
  }

  int fq = lane >> 4, fr = lane & 15;
  float xmv[4];
#pragma unroll
  for (int j = 0; j < 4; ++j) xmv[j] = xxb[m0 + wm * 64 + j * 16 + fr];
#pragma unroll
  for (int i = 0; i < 4; ++i) {
#pragma unroll
    for (int r = 0; r < 4; ++r) {
      int nl_ = wn * 64 + i * 16 + fq * 4 + r;
      float xn = xxb[n0 + nl_];
#pragma unroll
      for (int j = 0; j < 4; ++j) {
        int ml_ = wm * 64 + j * 16 + fr;
        outT[nl_ * 128 + ml_] = 2.f * acc[i][j][r] - xn - xmv[j];
      }
    }
  }
  __syncthreads();
#pragma unroll
  for (int v = 0; v < 16; ++v) {
    int row = v * 8 + (tid >> 5);
    int col = (tid & 31) * 4;
    *(float4*)(Db + (size_t)(n0 + row) * N + m0 + col) = *(float4*)&outT[row * 128 + col];
  }
}

// ---------------- top-K: 1 wave per row, bitwise radix-select, no LDS / no barriers ----------------
__global__ __launch_bounds__(256) void topk_kernel(const float* __restrict__ D, int* __restrict__ idxo,
                                                   int b0, int N, int Ktop) {
  int lane = threadIdx.x & 63, wv = threadIdx.x >> 6;
  int n = blockIdx.x * 4 + wv;
  int bz = blockIdx.y;
  const float* row = D + (size_t)bz * N * N + (size_t)n * N;

  unsigned u[32];
#pragma unroll
  for (int g = 0; g < 8; ++g) {
    float4 v = *(const float4*)(row + g * 256 + lane * 4);
    unsigned x;
    x = __float_as_uint(v.x); u[g * 4 + 0] = (x & 0x80000000u) ? ~x : (x | 0x80000000u);
    x = __float_as_uint(v.y); u[g * 4 + 1] = (x & 0x80000000u) ? ~x : (x | 0x80000000u);
    x = __float_as_uint(v.z); u[g * 4 + 2] = (x & 0x80000000u) ? ~x : (x | 0x80000000u);
    x = __float_as_uint(v.w); u[g * 4 + 3] = (x & 0x80000000u) ? ~x : (x | 0x80000000u);
  }

  const unsigned K = (unsigned)Ktop;
  unsigned prefix = 0;
  bool exact = false;
#pragma unroll 1
  for (int b = 31; b >= 0; --b) {
    unsigned cand = prefix | (1u << b);
    int c = 0;
#pragma unroll
    for (int j = 0; j < 32; ++j) c += (u[j] >= cand) ? 1 : 0;
#pragma unroll
    for (int off = 32; off >= 1; off >>= 1) c += __shfl_xor(c, off, 64);
    if ((unsigned)c >= K) {
      prefix = cand;
      if ((unsigned)c == K) { exact = true; break; }
    }
  }

  int* out = idxo + ((size_t)(b0 + bz) * N + n) * Ktop;
  int base = 0;
#pragma unroll
  for (int j = 0; j < 32; ++j) {
    bool s = exact ? (u[j] >= prefix) : (u[j] > prefix);
    unsigned long long mask = __ballot(s);
    if (s) {
      int pos = base + (int)__popcll(mask & ((1ull << lane) - 1ull));
      out[pos] = (j >> 2) * 256 + lane * 4 + (j & 3);
    }
    base += (int)__popcll(mask);
  }
  if (!exact) {
    int kf = (int)K - base;
    int last = -1;
    for (int s2 = 0; s2 < kf; ++s2) {
      int local = 0x7FFFFFFF;
#pragma unroll
      for (int j = 0; j < 32; ++j)
        if (u[j] == prefix) {
          int m = (j >> 2) * 256 + lane * 4 + (j & 3);
          if (m > last && m < local) local = m;
        }
#pragma unroll
      for (int off = 32; off >= 1; off >>= 1) {
        int o = __shfl_xor(local, off, 64);
        local = o < local ? o : local;
      }
      if (lane == 0) out[base + s2] = local;
      last = local;
    }
  }
}

// ---------------- gather + max over K + scale/bias/leaky (float4) ----------------
__global__ __launch_bounds__(256) void gathermax_kernel(const float* __restrict__ YZ, int ldyz, int cout,
                                                        const int* __restrict__ idxo,
                                                        const float* __restrict__ g, const float* __restrict__ bias,
                                                        float* __restrict__ outp, int ldo, int N, int Ktop,
                                                        int total4) {
  int t = blockIdx.x * 256 + threadIdx.x;
  if (t >= total4) return;
  int cq = cout >> 2;
  int dq = t % cq, bn = t / cq;
  int d0 = dq * 4;
  int b = bn / N;
  const int* ip = idxo + (size_t)bn * Ktop;
  float4 gv = *(const float4*)(g + d0);
  float4 bv = *(const float4*)(bias + d0);
  float4 zv = *(const float4*)(YZ + (size_t)bn * ldyz + cout + d0);
  bool px = gv.x >= 0.f, py = gv.y >= 0.f, pz = gv.z >= 0.f, pw = gv.w >= 0.f;
  float4 best;
  best.x = px ? -FLT_MAX : FLT_MAX;
  best.y = py ? -FLT_MAX : FLT_MAX;
  best.z = pz ? -FLT_MAX : FLT_MAX;
  best.w = pw ? -FLT_MAX : FLT_MAX;
  for (int k = 0; k < Ktop; ++k) {
    int m = ip[k];
    float4 y = *(const float4*)(YZ + ((size_t)b * N + m) * ldyz + d0);
    best.x = px ? fmaxf(best.x, y.x) : fminf(best.x, y.x);
    best.y = py ? fmaxf(best.y, y.y) : fminf(best.y, y.y);
    best.z = pz ? fmaxf(best.z, y.z) : fminf(best.z, y.z);
    best.w = pw ? fmaxf(best.w, y.w) : fminf(best.w, y.w);
  }
  float4 o;
  float h;
  h = (best.x + zv.x) * gv.x + bv.x; o.x = h >= 0.f ? h : NSLOPE * h;
  h = (best.y + zv.y) * gv.y + bv.y; o.y = h >= 0.f ? h : NSLOPE * h;
  h = (best.z + zv.z) * gv.z + bv.z; o.z = h >= 0.f ? h : NSLOPE * h;
  h = (best.w + zv.w) * gv.w + bv.w; o.w = h >= 0.f ? h : NSLOPE * h;
  *(float4*)(outp + (size_t)bn * ldo + d0) = o;
}

// ---------------- final GEMM via split-bf16 MFMA ----------------
// XCD-aware 1D grid swizzle: bid&7 = XCD; each XCD owns 16 contiguous row-tiles so
// XC row-tiles are fetched into exactly one per-XCD L2 (FETCH 133MB -> ~40MB expected).
// W-staging uses XOR k-group swizzle to cut 16-way LDS write conflicts to 4-way.
__global__ __launch_bounds__(256) void mfma_out_kernel(const float* __restrict__ XC,
                                                       const float* __restrict__ W,
                                                       const float* __restrict__ g,
                                                       const float* __restrict__ bias,
                                                       float* __restrict__ outp) {
  __shared__ ushort Ws_hi[128 * 40];
  __shared__ ushort Ws_lo[128 * 40];
  __shared__ ushort Xs_hi[128 * 40];
  __shared__ ushort Xs_lo[128 * 40];
  const int tid = threadIdx.x;
  const int lane = tid & 63, w = tid >> 6;
  const int wd = w & 1, wn = w >> 1;
  int bid = blockIdx.x;                 // 0..1023
  int xcd = bid & 7, jj = bid >> 3;     // 128 blocks per XCD
  const int row0 = (xcd * 16 + (jj >> 3)) * 128;  // m (row-tile: 16 per XCD, contiguous)
  const int col0 = (jj & 7) * 128;                // d
  f32x4 acc[4][4] = {};

  for (int k0 = 0; k0 < 512; k0 += 32) {
#pragma unroll
    for (int e = 0; e < 4; ++e) {
      int flat = tid + e * 256;
      int r = flat >> 3;
      int c4 = (flat & 7) * 4;
      float4 v = *(const float4*)(XC + (size_t)(row0 + r) * 512 + k0 + c4);
      ushort4 h, l;
      bsplit(v.x, h.x, l.x); bsplit(v.y, h.y, l.y);
      bsplit(v.z, h.z, l.z); bsplit(v.w, h.w, l.w);
      *(ushort4*)&Xs_hi[r * 40 + c4] = h;
      *(ushort4*)&Xs_lo[r * 40 + c4] = l;
    }
#pragma unroll
    for (int e = 0; e < 4; ++e) {
      int flat = tid + e * 256;
      int k = (flat >> 6) * 2;
      int c2 = (flat & 63) * 2;
      float2 v0 = *(const float2*)(W + (size_t)(k0 + k) * 1024 + col0 + c2);
      float2 v1 = *(const float2*)(W + (size_t)(k0 + k + 1) * 1024 + col0 + c2);
      ushort h00, h01, h10, h11, l00, l01, l10, l11;
      bsplit(v0.x, h00, l00); bsplit(v0.y, h01, l01);
      bsplit(v1.x, h10, l10); bsplit(v1.y, h11, l11);
      // XOR k-group swizzle (same for rows c2 and c2+1 since c2 is even)
      int ksw = (((k >> 3) ^ ((c2 >> 3) & 3)) << 3) + (k & 7);
      *(uint*)&Ws_hi[c2 * 40 + ksw]       = (uint)h00 | ((uint)h10 << 16);
      *(uint*)&Ws_hi[(c2 + 1) * 40 + ksw] = (uint)h01 | ((uint)h11 << 16);
      *(uint*)&Ws_lo[c2 * 40 + ksw]       = (uint)l00 | ((uint)l10 << 16);
      *(uint*)&Ws_lo[(c2 + 1) * 40 + ksw] = (uint)l01 | ((uint)l11 << 16);
    }
    __syncthreads();
    short8v wh[4], wl[4], xh[4], xl[4];
    int kg = (lane >> 4) * 8;
    int lr = lane & 15;
#pragma unroll
    for (int i = 0; i < 4; ++i) {
      int rr = wd * 64 + i * 16 + lr;
      int gsw = (((lane >> 4) ^ ((rr >> 3) & 3)) << 3);
      wh[i] = *(const short8v*)&Ws_hi[rr * 40 + gsw];
      wl[i] = *(const short8v*)&Ws_lo[rr * 40 + gsw];
      xh[i] = *(const short8v*)&Xs_hi[(wn * 64 + i * 16 + lr) * 40 + kg];
      xl[i] = *(const short8v*)&Xs_lo[(wn * 64 + i * 16 + lr) * 40 + kg];
    }
#pragma unroll
    for (int i = 0; i < 4; ++i)
#pragma unroll
      for (int j = 0; j < 4; ++j) {
        acc[i][j] = __builtin_amdgcn_mfma_f32_16x16x32_bf16(wh[i], xh[j], acc[i][j], 0, 0, 0);
        acc[i][j] = __builtin_amdgcn_mfma_f32_16x16x32_bf16(wh[i], xl[j], acc[i][j], 0, 0, 0);
        acc[i][j] = __builtin_amdgcn_mfma_f32_16x16x32_bf16(wl[i], xh[j], acc[i][j], 0, 0, 0);
      }
    __syncthreads();
  }
  int fq = lane >> 4, fr = lane & 15;
#pragma unroll
  for (int i = 0; i < 4; ++i) {
#pragma unroll
    for (int r = 0; r < 4; ++r) {
      int d = col0 + wd * 64 + i * 16 + fq * 4 + r;
      float gv = g[d], bv = bias[d];
#pragma unroll
      for (int j = 0; j < 4; ++j) {
        int mrow = row0 + wn * 64 + j * 16 + fr;
        int batch = mrow >> 11, n = mrow & 2047;
        float h = acc[i][j][r] * gv + bv;
        h = h >= 0.f ? h : NSLOPE * h;
        outp[(((size_t)batch << 10) + d) * 2048 + n] = h;
      }
    }
  }
}

extern "C" void kernel_launch(void* const* d_in, const int* in_sizes, int n_in,
                              void* d_out, int out_size, void* d_ws, size_t ws_size,
                              hipStream_t stream) {
  const int B = 8, N = 2048, Ktop = 20;
  const int M = B * N;  // 16384

  const float* pts = (const float*)d_in[0];
  const float* W1 = (const float*)d_in[1];  const float* g1 = (const float*)d_in[2];  const float* b1 = (const float*)d_in[3];
  const float* W2 = (const float*)d_in[4];  const float* g2 = (const float*)d_in[5];  const float* b2 = (const float*)d_in[6];
  const float* W3 = (const float*)d_in[7];  const float* g3 = (const float*)d_in[8];  const float* b3 = (const float*)d_in[9];
  const float* W4 = (const float*)d_in[10]; const float* g4 = (const float*)d_in[11]; const float* b4 = (const float*)d_in[12];
  const float* W5 = (const float*)d_in[13]; const float* g5 = (const float*)d_in[14]; const float* b5 = (const float*)d_in[15];

  float* p = (float*)d_ws;
  float* XC = p;  p += (size_t)M * 512;        // concat feature buffer [x1|x2|x3|x4]
  float* Wc = p;  p += 128 * 512;              // combined weight, max cin*2cout
  float* xx = p;  p += M;                      // per-point sum of squares
  int* idxb = (int*)p; p = (float*)(idxb + (size_t)M * Ktop);
  float* shared = p;                           // D / YZ overlap (disjoint lifetimes)
  size_t shared_bytes = ws_size - (size_t)((char*)shared - (char*)d_ws);
  float* D = shared;
  float* YZ = shared;
  int chunk = (int)(shared_bytes / ((size_t)N * N * sizeof(float)));
  if (chunk > B) chunk = B;
  if (chunk < 1) chunk = 1;

  auto knn = [&](const float* Xp, int ldx, int C) {
    sumsq_kernel<<<(M + 255) / 256, 256, 0, stream>>>(Xp, ldx, C, xx, M);
    for (int b0 = 0; b0 < B; b0 += chunk) {
      int nb = (B - b0 < chunk) ? (B - b0) : chunk;
      mfma_dist_kernel<<<dim3(N / 128, N / 128, nb), 256, 65536, stream>>>(Xp, ldx, C, xx, D, b0, N);
      topk_kernel<<<dim3(N / 4, nb), 256, 0, stream>>>(D, idxb, b0, N, Ktop);
    }
  };

  auto econv = [&](const float* Xp, int ldx, int cin, int cout,
                   const float* W, const float* g, const float* bb, float* outp) {
    int tot = cin * 2 * cout;
    wcprep_kernel<<<(tot + 255) / 256, 256, 0, stream>>>(W, cin, cout, Wc);
    gemm_kernel<<<dim3(2 * cout / 64, M / 64), 256, 0, stream>>>(Xp, ldx, Wc, 2 * cout, YZ, 2 * cout, M, 2 * cout, cin);
    int total4 = B * N * (cout / 4);
    gathermax_kernel<<<(total4 + 255) / 256, 256, 0, stream>>>(YZ, 2 * cout, cout, idxb, g, bb, outp, 512, N, Ktop, total4);
  };

  knn(pts, 3, 3);
  econv(pts, 3, 3, 64, W1, g1, b1, XC + 0);
  knn(XC + 0, 512, 64);
  econv(XC + 0, 512, 64, 64, W2, g2, b2, XC + 64);
  knn(XC + 64, 512, 64);
  econv(XC + 64, 512, 64, 128, W3, g3, b3, XC + 128);
  knn(XC + 128, 512, 128);
  econv(XC + 128, 512, 128, 256, W4, g4, b4, XC + 256);

  // final: fused split-bf16 MFMA GEMM, XCD-swizzled 1D grid
  mfma_out_kernel<<<1024, 256, 0, stream>>>(XC, W5, g5, b5, (float*)d_out);
}